// Round 12
// baseline (230.215 us; speedup 1.0000x reference)
//
#include <hip/hip_runtime.h>
#include <math.h>

#define H_ 192
#define W_ 192
#define HW_ (H_*W_)      // 36864
#define B_ 2
#define C_ 64
#define NPIX_ (B_*HW_)   // 73728
#define EPSV 1e-5f

typedef short s8v  __attribute__((ext_vector_type(8)));
typedef float f4v  __attribute__((ext_vector_type(4)));

__device__ __forceinline__ unsigned short f2bf(float f) {
    union { float f; unsigned u; } x; x.f = f;
    unsigned r = x.u + 0x7fffu + ((x.u >> 16) & 1u);   // RNE
    return (unsigned short)(r >> 16);
}
__device__ __forceinline__ float bf2f(unsigned short h) {
    union { unsigned u; float f; } x; x.u = ((unsigned)h) << 16; return x.f;
}

// ---------------------------------------------------------------------------
// Fold: w1t[c][o] = w1[o][c];
//       wkT[k][p][c]  = bf16( sum_o w2[p,o]*dw[o,c,k] )   (deform weights)
//       wOff[k][oc32][c] = bf16( ow[oc][c][k] ), oc>=18 zero  (offconv weights)
//       beff[p] = sum_o w2[p,o]*db[o] + b2[p]
// ---------------------------------------------------------------------------
__global__ void k_fold(const float* __restrict__ w1, const float* __restrict__ w2,
                       const float* __restrict__ dw, const float* __restrict__ db,
                       const float* __restrict__ b2, const float* __restrict__ ow,
                       float* __restrict__ w1t, unsigned short* __restrict__ wkT,
                       unsigned short* __restrict__ wOff, float* __restrict__ beff)
{
    int tid = blockIdx.x * 256 + threadIdx.x;   // 0..36863
    if (tid < 9 * 64 * 64) {
        int k = tid >> 12;
        int r = tid & 4095;
        int c = r >> 6;
        int p = r & 63;
        float acc = 0.f;
        #pragma unroll 8
        for (int o = 0; o < 64; ++o)
            acc = fmaf(w2[p * 64 + o], dw[(o * 64 + c) * 9 + k], acc);
        wkT[(k << 12) + (p << 6) + c] = f2bf(acc);
    }
    if (tid < 9 * 32 * 64) {       // offconv weights, padded to 32 oc
        int k = tid >> 11;
        int r = tid & 2047;
        int oc = r >> 6;
        int c = r & 63;
        float v = (oc < 18) ? ow[((oc * 64) + c) * 9 + k] : 0.f;
        wOff[tid] = f2bf(v);
    }
    if (tid < 4096) {
        int c = tid >> 6, o = tid & 63;
        w1t[c * 64 + o] = w1[o * 64 + c];
    }
    if (tid < 64) {
        float acc = b2[tid];
        #pragma unroll 8
        for (int o = 0; o < 64; ++o) acc = fmaf(w2[tid * 64 + o], db[o], acc);
        beff[tid] = acc;
    }
}

// ---------------------------------------------------------------------------
// conv1x1 #1 (fp32 VALU): y = x * w1t + b1  (raw, pre-BN)
// ---------------------------------------------------------------------------
__global__ __launch_bounds__(256) void k_conv1x1(const float* __restrict__ x,
        const float* __restrict__ w1t, const float* __restrict__ b1,
        float* __restrict__ y)
{
    __shared__ __align__(16) float xs[64][64];   // [c][p]
    __shared__ __align__(16) float wsh[64][64];  // [c][o]
    int t = threadIdx.x;
    int base = blockIdx.x * 64;
    int b = base / HW_;
    int hw0 = base % HW_;

    #pragma unroll
    for (int i = 0; i < 16; ++i) {
        int e = t + i * 256;
        ((float*)wsh)[e] = w1t[e];
    }
    int p = t & 63, cg = t >> 6;
    #pragma unroll
    for (int i = 0; i < 16; ++i) {
        int c = cg * 16 + i;
        xs[c][p] = x[(b * 64 + c) * HW_ + hw0 + p];
    }
    __syncthreads();

    int l = t & 63, wv = t >> 6;
    int pg = l & 15;
    int og = wv * 4 + (l >> 4);
    float acc[4][4];
    #pragma unroll
    for (int i = 0; i < 4; ++i)
        #pragma unroll
        for (int j = 0; j < 4; ++j) acc[i][j] = 0.f;

    #pragma unroll 8
    for (int c = 0; c < 64; ++c) {
        float va[4], wa[4];
        *(float4*)va = *(const float4*)&xs[c][pg * 4];
        *(float4*)wa = *(const float4*)&wsh[c][og * 4];
        #pragma unroll
        for (int i = 0; i < 4; ++i)
            #pragma unroll
            for (int j = 0; j < 4; ++j)
                acc[i][j] = fmaf(va[i], wa[j], acc[i][j]);
    }

    #pragma unroll
    for (int j = 0; j < 4; ++j) {
        int oc = og * 4 + j;
        float bias = b1[oc];
        float4 o4 = make_float4(acc[0][j] + bias, acc[1][j] + bias,
                                acc[2][j] + bias, acc[3][j] + bias);
        *(float4*)&y[(b * 64 + oc) * HW_ + hw0 + pg * 4] = o4;
    }
}

// ---------------------------------------------------------------------------
// BN stats: one block per channel; writes scale, shift
// ---------------------------------------------------------------------------
__global__ void k_stats(const float* __restrict__ y, const float* __restrict__ g,
                        const float* __restrict__ be, float* __restrict__ scsh)
{
    int c = blockIdx.x;
    int t = threadIdx.x;
    float s = 0.f, sq = 0.f;
    for (int b = 0; b < B_; ++b) {
        const float4* p4 = (const float4*)&y[(b * 64 + c) * HW_];
        for (int i = t; i < HW_ / 4; i += 256) {
            float4 v = p4[i];
            s += v.x + v.y + v.z + v.w;
            sq += v.x * v.x + v.y * v.y + v.z * v.z + v.w * v.w;
        }
    }
    int lane = t & 63, wv = t >> 6;
    #pragma unroll
    for (int off = 32; off > 0; off >>= 1) {
        s += __shfl_down(s, off);
        sq += __shfl_down(sq, off);
    }
    __shared__ float red[8];
    if (lane == 0) { red[wv] = s; red[4 + wv] = sq; }
    __syncthreads();
    if (t == 0) {
        float S = red[0] + red[1] + red[2] + red[3];
        float Q = red[4] + red[5] + red[6] + red[7];
        float m = S / (float)NPIX_;
        float var = Q / (float)NPIX_ - m * m;
        float sc = g[c] * rsqrtf(var + EPSV);
        scsh[c] = sc;
        scsh[64 + c] = be[c] - m * sc;
    }
}

// ---------------------------------------------------------------------------
// BN apply, in place, float4 (used for final BN2 only)
// ---------------------------------------------------------------------------
__global__ void k_bn(float* __restrict__ y, const float* __restrict__ scsh, int relu)
{
    int idx = blockIdx.x * 256 + threadIdx.x;         // float4 index
    int c = ((idx * 4) / HW_) & 63;
    float sc = scsh[c], sh = scsh[64 + c];
    float4 v = ((float4*)y)[idx];
    v.x = fmaf(v.x, sc, sh);
    v.y = fmaf(v.y, sc, sh);
    v.z = fmaf(v.z, sc, sh);
    v.w = fmaf(v.w, sc, sh);
    if (relu) {
        v.x = fmaxf(v.x, 0.f); v.y = fmaxf(v.y, 0.f);
        v.z = fmaxf(v.z, 0.f); v.w = fmaxf(v.w, 0.f);
    }
    ((float4*)y)[idx] = v;
}

// ---------------------------------------------------------------------------
// BN1+ReLU -> bf16 NHWC copy ONLY. Thread = 32 ch of one pixel.
// ---------------------------------------------------------------------------
__global__ __launch_bounds__(256) void k_bntr(const float* __restrict__ A,
        const float* __restrict__ scsh, unsigned short* __restrict__ Abf)
{
    __shared__ float scb[64], shb[64];
    int t = threadIdx.x;
    int wg = blockIdx.x;
    int nid = (wg & 7) * 72 + (wg >> 3);     // XCD-chunked over 576
    int base = nid * 128;                    // global pixel base
    int b = base / HW_;
    int hw0 = base % HW_;

    if (t < 64) { scb[t] = scsh[t]; shb[t] = scsh[64 + t]; }
    __syncthreads();

    int pl = t & 127;          // pixel within block
    int chalf = t >> 7;        // 0 or 1 -> channels 32*chalf..+32
    int hw = hw0 + pl;
    size_t gpx = (size_t)base + pl;

    unsigned pk[16];
    #pragma unroll
    for (int c = 0; c < 32; ++c) {
        int ch = chalf * 32 + c;
        size_t idx = ((size_t)(b * 64 + ch)) * HW_ + hw;
        float a = A[idx];
        float v = fmaxf(fmaf(a, scb[ch], shb[ch]), 0.f);
        unsigned bf = f2bf(v);
        if (c & 1) pk[c >> 1] |= bf << 16; else pk[c >> 1] = bf;
    }
    unsigned short* dst = Abf + (gpx << 6) + chalf * 32;
    #pragma unroll
    for (int j = 0; j < 4; ++j)
        *(int4*)&dst[j * 8] = make_int4((int)pk[4 * j], (int)pk[4 * j + 1],
                                        (int)pk[4 * j + 2], (int)pk[4 * j + 3]);
}

// ---------------------------------------------------------------------------
// offset conv3x3 via bf16 MFMA on Abf (NHWC): implicit GEMM, zero pad.
// ---------------------------------------------------------------------------
__global__ __launch_bounds__(64) void k_offconv(const unsigned short* __restrict__ Abf,
        const unsigned short* __restrict__ wOff, const float* __restrict__ ob,
        float* __restrict__ off)
{
    int t = threadIdx.x;
    int wg = blockIdx.x;
    int nid = (wg & 7) * 576 + (wg >> 3);        // XCD-chunked over 4608
    int base = nid * 16;
    int b = base / HW_;
    int hw0 = base % HW_;
    int h = hw0 / W_;
    int w0 = hw0 % W_;

    int m = t & 15, q = t >> 4;
    int wx = w0 + m;
    const unsigned short* Ap = Abf + (((size_t)b * HW_) << 6);
    int cA = q * 8, cB = 32 + q * 8;

    f4v acc0 = (f4v){0.f, 0.f, 0.f, 0.f};
    f4v acc1 = (f4v){0.f, 0.f, 0.f, 0.f};
    const s8v zr = {0, 0, 0, 0, 0, 0, 0, 0};

    #pragma unroll
    for (int k = 0; k < 9; ++k) {
        int yy = h + k / 3 - 1;
        int xx = wx + k % 3 - 1;
        bool valid = (yy >= 0) && (yy < H_) && (xx >= 0) && (xx < W_);
        int yc = min(max(yy, 0), H_ - 1);
        int xc = min(max(xx, 0), W_ - 1);
        size_t ip = (size_t)(yc * W_ + xc) << 6;
        s8v a0 = *(const s8v*)&Ap[ip + cA];
        s8v a1 = *(const s8v*)&Ap[ip + cB];
        if (!valid) { a0 = zr; a1 = zr; }

        const unsigned short* wb = wOff + ((size_t)k << 11);
        s8v b00 = *(const s8v*)&wb[m * 64 + q * 8];
        s8v b01 = *(const s8v*)&wb[m * 64 + 32 + q * 8];
        s8v b10 = *(const s8v*)&wb[(16 + m) * 64 + q * 8];
        s8v b11 = *(const s8v*)&wb[(16 + m) * 64 + 32 + q * 8];

        acc0 = __builtin_amdgcn_mfma_f32_16x16x32_bf16(a0, b00, acc0, 0, 0, 0);
        acc0 = __builtin_amdgcn_mfma_f32_16x16x32_bf16(a1, b01, acc0, 0, 0, 0);
        acc1 = __builtin_amdgcn_mfma_f32_16x16x32_bf16(a0, b10, acc1, 0, 0, 0);
        acc1 = __builtin_amdgcn_mfma_f32_16x16x32_bf16(a1, b11, acc1, 0, 0, 0);
    }

    float biasLo = ob[m];
    float biasHi = (m < 2) ? ob[16 + m] : 0.f;
    #pragma unroll
    for (int r = 0; r < 4; ++r) {
        int px = q * 4 + r;
        off[((size_t)b * 18 + m) * HW_ + hw0 + px] = acc0[r] + biasLo;
        if (m < 2)
            off[((size_t)b * 18 + 16 + m) * HW_ + hw0 + px] = acc1[r] + biasHi;
    }
}

// ---------------------------------------------------------------------------
// R12a: bilinear gather -> V[k][pixL][64] bf16, per pixel chunk.
// Thread = (pixel, tap, 16-ch group). No acc state, no MFMA -> pure TLP
// hides gather latency (20+ waves/SIMD). Blocks ordered pixel-major so the
// XCD swizzle gives each XCD a contiguous pixel range (shared with k_dgemm).
// ---------------------------------------------------------------------------
__global__ __launch_bounds__(256) void k_gather(const unsigned short* __restrict__ Abf,
        const float* __restrict__ offb, unsigned short* __restrict__ V,
        int basePix, int P)
{
    int t = threadIdx.x;
    int wg = blockIdx.x;
    int nblk = (P >> 6) * 9;
    int nid = (wg & 7) * (nblk >> 3) + (wg >> 3);   // XCD-chunked
    int pixblk = nid / 9;
    int k = nid - pixblk * 9;

    int pl = t & 63;
    int cg = t >> 6;                 // 16-ch group 0..3
    int pixL = pixblk * 64 + pl;
    int gp = basePix + pixL;
    int b = gp / HW_;
    int hw = gp - b * HW_;
    int h = hw / W_;
    int wx = hw - h * W_;

    float dy = offb[(b * 18 + 2 * k) * HW_ + hw];
    float dx = offb[(b * 18 + 2 * k + 1) * HW_ + hw];
    float py = (float)(h + k / 3 - 1) + dy;
    float px = (float)(wx + k % 3 - 1) + dx;
    float fly = floorf(py), flx = floorf(px);
    float fy = py - fly, fx = px - flx;
    int y0i = (int)fly, x0i = (int)flx;
    float w00 = (1.f - fy) * (1.f - fx);
    float w01 = (1.f - fy) * fx;
    float w10 = fy * (1.f - fx);
    float w11 = fy * fx;
    bool yv0 = (y0i >= 0) && (y0i < H_);
    bool yv1 = (y0i + 1 >= 0) && (y0i + 1 < H_);
    bool xv0 = (x0i >= 0) && (x0i < W_);
    bool xv1 = (x0i + 1 >= 0) && (x0i + 1 < W_);
    if (!(yv0 && xv0)) w00 = 0.f;
    if (!(yv0 && xv1)) w01 = 0.f;
    if (!(yv1 && xv0)) w10 = 0.f;
    if (!(yv1 && xv1)) w11 = 0.f;
    int yc0 = min(max(y0i, 0), H_ - 1), yc1 = min(max(y0i + 1, 0), H_ - 1);
    int xc0 = min(max(x0i, 0), W_ - 1), xc1 = min(max(x0i + 1, 0), W_ - 1);
    size_t i00 = (size_t)(yc0 * W_ + xc0) << 6;
    size_t i01 = (size_t)(yc0 * W_ + xc1) << 6;
    size_t i10 = (size_t)(yc1 * W_ + xc0) << 6;
    size_t i11 = (size_t)(yc1 * W_ + xc1) << 6;

    const unsigned short* Ap = Abf + (((size_t)b * HW_) << 6);
    int c0 = cg * 16;
    s8v v00a = *(const s8v*)&Ap[i00 + c0], v00b = *(const s8v*)&Ap[i00 + c0 + 8];
    s8v v01a = *(const s8v*)&Ap[i01 + c0], v01b = *(const s8v*)&Ap[i01 + c0 + 8];
    s8v v10a = *(const s8v*)&Ap[i10 + c0], v10b = *(const s8v*)&Ap[i10 + c0 + 8];
    s8v v11a = *(const s8v*)&Ap[i11 + c0], v11b = *(const s8v*)&Ap[i11 + c0 + 8];

    unsigned pk[8];
    #pragma unroll
    for (int i = 0; i < 4; ++i) {
        unsigned wa = 0, wb = 0;
        #pragma unroll
        for (int jj = 0; jj < 2; ++jj) {
            int e = 2 * i + jj;
            float va = bf2f((unsigned short)v00a[e]) * w00
                     + bf2f((unsigned short)v01a[e]) * w01
                     + bf2f((unsigned short)v10a[e]) * w10
                     + bf2f((unsigned short)v11a[e]) * w11;
            wa |= ((unsigned)f2bf(va)) << (16 * jj);
            float vb = bf2f((unsigned short)v00b[e]) * w00
                     + bf2f((unsigned short)v01b[e]) * w01
                     + bf2f((unsigned short)v10b[e]) * w10
                     + bf2f((unsigned short)v11b[e]) * w11;
            wb |= ((unsigned)f2bf(vb)) << (16 * jj);
        }
        pk[i] = wa; pk[4 + i] = wb;
    }
    unsigned short* dst = V + ((((size_t)k * P + pixL) << 6) + c0);
    *(int4*)dst       = make_int4((int)pk[0], (int)pk[1], (int)pk[2], (int)pk[3]);
    *(int4*)(dst + 8) = make_int4((int)pk[4], (int)pk[5], (int)pk[6], (int)pk[7]);
}

// ---------------------------------------------------------------------------
// R12b: streaming MFMA GEMM over V: out[px][oc] = sum_k sum_c V[k][px][c]*W.
// 1 wave/block = 16px x 64oc; A loads are LINEAR (coalesced dwordx4) — no
// gather, no latency chain; V is L2-resident (same XCD pixel ranges).
// ---------------------------------------------------------------------------
__global__ __launch_bounds__(64) void k_dgemm(const unsigned short* __restrict__ V,
        const unsigned short* __restrict__ wkT, const float* __restrict__ beff,
        float* __restrict__ out, int basePix, int P)
{
    int t = threadIdx.x;
    int wg = blockIdx.x;
    int nblk = P >> 4;
    int nid = (wg & 7) * (nblk >> 3) + (wg >> 3);   // XCD-chunked
    int pixW = nid * 16;

    int m = t & 15, q = t >> 4;

    f4v acc[4];
    #pragma unroll
    for (int n = 0; n < 4; ++n) acc[n] = (f4v){0.f, 0.f, 0.f, 0.f};

    #pragma unroll
    for (int k = 0; k < 9; ++k) {
        const unsigned short* Vk = V + (((size_t)k * P + pixW) << 6);
        s8v a0 = *(const s8v*)&Vk[(m << 6) + q * 8];
        s8v a1 = *(const s8v*)&Vk[(m << 6) + 32 + q * 8];
        const unsigned short* wkb = wkT + ((size_t)k << 12);
        #pragma unroll
        for (int n = 0; n < 4; ++n) {
            int oc = n * 16 + m;
            s8v b0 = *(const s8v*)&wkb[oc * 64 + q * 8];
            s8v b1 = *(const s8v*)&wkb[oc * 64 + 32 + q * 8];
            acc[n] = __builtin_amdgcn_mfma_f32_16x16x32_bf16(a0, b0, acc[n], 0, 0, 0);
            acc[n] = __builtin_amdgcn_mfma_f32_16x16x32_bf16(a1, b1, acc[n], 0, 0, 0);
        }
    }

    int gp0 = basePix + pixW;
    int b = gp0 / HW_;
    int hw0 = gp0 - b * HW_;
    #pragma unroll
    for (int n = 0; n < 4; ++n) {
        int oc = n * 16 + m;
        float bias = beff[oc];
        #pragma unroll
        for (int r = 0; r < 4; ++r)
            out[((size_t)b * 64 + oc) * HW_ + hw0 + q * 4 + r] = acc[n][r] + bias;
    }
}

// ---------------------------------------------------------------------------
extern "C" void kernel_launch(void* const* d_in, const int* in_sizes, int n_in,
                              void* d_out, int out_size, void* d_ws, size_t ws_size,
                              hipStream_t stream)
{
    const float* x   = (const float*)d_in[0];
    const float* w1  = (const float*)d_in[1];
    const float* b1  = (const float*)d_in[2];
    const float* g1  = (const float*)d_in[3];
    const float* be1 = (const float*)d_in[4];
    const float* ow  = (const float*)d_in[5];
    const float* ob  = (const float*)d_in[6];
    const float* dw  = (const float*)d_in[7];
    const float* db  = (const float*)d_in[8];
    const float* w2  = (const float*)d_in[9];
    const float* b2  = (const float*)d_in[10];
    const float* g2  = (const float*)d_in[11];
    const float* be2 = (const float*)d_in[12];
    float* out = (float*)d_out;

    float* ws    = (float*)d_ws;
    float* A     = ws;                           // conv1x1 out (raw fp32)
    float* offb  = A + (size_t)NPIX_ * 64;       // 1,327,104 floats
    float* w1t   = offb + (size_t)B_ * 18 * HW_;
    unsigned short* wkT  = (unsigned short*)(w1t + 4096);   // 36,864 bf16
    unsigned short* wOff = wkT + 9 * 4096;                   // 18,432 bf16
    float* beff  = (float*)(wOff + 9 * 2048);
    float* scsh1 = beff + 64;                    // 128
    float* scsh2 = scsh1 + 128;                  // 128
    unsigned short* Abf = (unsigned short*)(scsh2 + 128);   // NPIX_*64 bf16
    unsigned short* V   = Abf + (size_t)NPIX_ * 64;          // gather staging

    // choose chunk count from workspace budget (deterministic per harness)
    size_t baseBytes = (size_t)((char*)V - (char*)d_ws);
    int CH = 8;
    if (ws_size >= baseBytes + (size_t)9 * 36864 * 64 * 2 * 2) CH = 2;
    else if (ws_size >= baseBytes + (size_t)9 * 18432 * 64 * 2 * 2) CH = 4;
    int P = NPIX_ / CH;

    hipLaunchKernelGGL(k_fold, dim3(144), dim3(256), 0, stream,
                       w1, w2, dw, db, b2, ow, w1t, wkT, wOff, beff);
    hipLaunchKernelGGL(k_conv1x1, dim3(NPIX_ / 64), dim3(256), 0, stream,
                       x, w1t, b1, A);
    hipLaunchKernelGGL(k_stats, dim3(64), dim3(256), 0, stream, A, g1, be1, scsh1);
    hipLaunchKernelGGL(k_bntr, dim3(NPIX_ / 128), dim3(256), 0, stream,
                       A, scsh1, Abf);
    hipLaunchKernelGGL(k_offconv, dim3(NPIX_ / 16), dim3(64), 0, stream,
                       Abf, wOff, ob, offb);
    for (int cp = 0; cp < CH; ++cp) {
        hipLaunchKernelGGL(k_gather, dim3((P / 64) * 9), dim3(256), 0, stream,
                           Abf, offb, V, cp * P, P);
        hipLaunchKernelGGL(k_dgemm, dim3(P / 16), dim3(64), 0, stream,
                           V, wkT, beff, out, cp * P, P);
    }
    hipLaunchKernelGGL(k_stats, dim3(64), dim3(256), 0, stream, out, g2, be2, scsh2);
    hipLaunchKernelGGL(k_bn, dim3((NPIX_ * 64 / 4) / 256), dim3(256), 0, stream,
                       out, scsh2, 0);
}

// Round 13
// 212.291 us; speedup vs baseline: 1.0844x; 1.0844x over previous
//
#include <hip/hip_runtime.h>
#include <math.h>

#define H_ 192
#define W_ 192
#define HW_ (H_*W_)      // 36864
#define B_ 2
#define C_ 64
#define NPIX_ (B_*HW_)   // 73728
#define EPSV 1e-5f

typedef short s8v  __attribute__((ext_vector_type(8)));
typedef float f4v  __attribute__((ext_vector_type(4)));

__device__ __forceinline__ unsigned short f2bf(float f) {
    union { float f; unsigned u; } x; x.f = f;
    unsigned r = x.u + 0x7fffu + ((x.u >> 16) & 1u);   // RNE
    return (unsigned short)(r >> 16);
}
__device__ __forceinline__ float bf2f(unsigned short h) {
    union { unsigned u; float f; } x; x.u = ((unsigned)h) << 16; return x.f;
}

// ---------------------------------------------------------------------------
// Fold: w1t[c][o] = w1[o][c];
//       wkT[k][p][c]  = bf16( sum_o w2[p,o]*dw[o,c,k] )   (deform weights)
//       wOff[k][oc32][c] = bf16( ow[oc][c][k] ), oc>=18 zero  (offconv weights)
//       beff[p] = sum_o w2[p,o]*db[o] + b2[p]
// ---------------------------------------------------------------------------
__global__ void k_fold(const float* __restrict__ w1, const float* __restrict__ w2,
                       const float* __restrict__ dw, const float* __restrict__ db,
                       const float* __restrict__ b2, const float* __restrict__ ow,
                       float* __restrict__ w1t, unsigned short* __restrict__ wkT,
                       unsigned short* __restrict__ wOff, float* __restrict__ beff)
{
    int tid = blockIdx.x * 256 + threadIdx.x;   // 0..36863
    if (tid < 9 * 64 * 64) {
        int k = tid >> 12;
        int r = tid & 4095;
        int c = r >> 6;
        int p = r & 63;
        float acc = 0.f;
        #pragma unroll 8
        for (int o = 0; o < 64; ++o)
            acc = fmaf(w2[p * 64 + o], dw[(o * 64 + c) * 9 + k], acc);
        wkT[(k << 12) + (p << 6) + c] = f2bf(acc);
    }
    if (tid < 9 * 32 * 64) {       // offconv weights, padded to 32 oc
        int k = tid >> 11;
        int r = tid & 2047;
        int oc = r >> 6;
        int c = r & 63;
        float v = (oc < 18) ? ow[((oc * 64) + c) * 9 + k] : 0.f;
        wOff[tid] = f2bf(v);
    }
    if (tid < 4096) {
        int c = tid >> 6, o = tid & 63;
        w1t[c * 64 + o] = w1[o * 64 + c];
    }
    if (tid < 64) {
        float acc = b2[tid];
        #pragma unroll 8
        for (int o = 0; o < 64; ++o) acc = fmaf(w2[tid * 64 + o], db[o], acc);
        beff[tid] = acc;
    }
}

// ---------------------------------------------------------------------------
// conv1x1 #1 (fp32 VALU): y = x * w1t + b1  (raw, pre-BN)
// ---------------------------------------------------------------------------
__global__ __launch_bounds__(256) void k_conv1x1(const float* __restrict__ x,
        const float* __restrict__ w1t, const float* __restrict__ b1,
        float* __restrict__ y)
{
    __shared__ __align__(16) float xs[64][64];   // [c][p]
    __shared__ __align__(16) float wsh[64][64];  // [c][o]
    int t = threadIdx.x;
    int base = blockIdx.x * 64;
    int b = base / HW_;
    int hw0 = base % HW_;

    #pragma unroll
    for (int i = 0; i < 16; ++i) {
        int e = t + i * 256;
        ((float*)wsh)[e] = w1t[e];
    }
    int p = t & 63, cg = t >> 6;
    #pragma unroll
    for (int i = 0; i < 16; ++i) {
        int c = cg * 16 + i;
        xs[c][p] = x[(b * 64 + c) * HW_ + hw0 + p];
    }
    __syncthreads();

    int l = t & 63, wv = t >> 6;
    int pg = l & 15;
    int og = wv * 4 + (l >> 4);
    float acc[4][4];
    #pragma unroll
    for (int i = 0; i < 4; ++i)
        #pragma unroll
        for (int j = 0; j < 4; ++j) acc[i][j] = 0.f;

    #pragma unroll 8
    for (int c = 0; c < 64; ++c) {
        float va[4], wa[4];
        *(float4*)va = *(const float4*)&xs[c][pg * 4];
        *(float4*)wa = *(const float4*)&wsh[c][og * 4];
        #pragma unroll
        for (int i = 0; i < 4; ++i)
            #pragma unroll
            for (int j = 0; j < 4; ++j)
                acc[i][j] = fmaf(va[i], wa[j], acc[i][j]);
    }

    #pragma unroll
    for (int j = 0; j < 4; ++j) {
        int oc = og * 4 + j;
        float bias = b1[oc];
        float4 o4 = make_float4(acc[0][j] + bias, acc[1][j] + bias,
                                acc[2][j] + bias, acc[3][j] + bias);
        *(float4*)&y[(b * 64 + oc) * HW_ + hw0 + pg * 4] = o4;
    }
}

// ---------------------------------------------------------------------------
// BN stats: one block per channel; writes scale, shift
// ---------------------------------------------------------------------------
__global__ void k_stats(const float* __restrict__ y, const float* __restrict__ g,
                        const float* __restrict__ be, float* __restrict__ scsh)
{
    int c = blockIdx.x;
    int t = threadIdx.x;
    float s = 0.f, sq = 0.f;
    for (int b = 0; b < B_; ++b) {
        const float4* p4 = (const float4*)&y[(b * 64 + c) * HW_];
        for (int i = t; i < HW_ / 4; i += 256) {
            float4 v = p4[i];
            s += v.x + v.y + v.z + v.w;
            sq += v.x * v.x + v.y * v.y + v.z * v.z + v.w * v.w;
        }
    }
    int lane = t & 63, wv = t >> 6;
    #pragma unroll
    for (int off = 32; off > 0; off >>= 1) {
        s += __shfl_down(s, off);
        sq += __shfl_down(sq, off);
    }
    __shared__ float red[8];
    if (lane == 0) { red[wv] = s; red[4 + wv] = sq; }
    __syncthreads();
    if (t == 0) {
        float S = red[0] + red[1] + red[2] + red[3];
        float Q = red[4] + red[5] + red[6] + red[7];
        float m = S / (float)NPIX_;
        float var = Q / (float)NPIX_ - m * m;
        float sc = g[c] * rsqrtf(var + EPSV);
        scsh[c] = sc;
        scsh[64 + c] = be[c] - m * sc;
    }
}

// ---------------------------------------------------------------------------
// BN apply, in place, float4 (used for final BN2 only)
// ---------------------------------------------------------------------------
__global__ void k_bn(float* __restrict__ y, const float* __restrict__ scsh, int relu)
{
    int idx = blockIdx.x * 256 + threadIdx.x;         // float4 index
    int c = ((idx * 4) / HW_) & 63;
    float sc = scsh[c], sh = scsh[64 + c];
    float4 v = ((float4*)y)[idx];
    v.x = fmaf(v.x, sc, sh);
    v.y = fmaf(v.y, sc, sh);
    v.z = fmaf(v.z, sc, sh);
    v.w = fmaf(v.w, sc, sh);
    if (relu) {
        v.x = fmaxf(v.x, 0.f); v.y = fmaxf(v.y, 0.f);
        v.z = fmaxf(v.z, 0.f); v.w = fmaxf(v.w, 0.f);
    }
    ((float4*)y)[idx] = v;
}

// ---------------------------------------------------------------------------
// BN1+ReLU -> bf16 NHWC copy ONLY. Thread = 32 ch of one pixel.
// ---------------------------------------------------------------------------
__global__ __launch_bounds__(256) void k_bntr(const float* __restrict__ A,
        const float* __restrict__ scsh, unsigned short* __restrict__ Abf)
{
    __shared__ float scb[64], shb[64];
    int t = threadIdx.x;
    int wg = blockIdx.x;
    int nid = (wg & 7) * 72 + (wg >> 3);     // XCD-chunked over 576
    int base = nid * 128;                    // global pixel base
    int b = base / HW_;
    int hw0 = base % HW_;

    if (t < 64) { scb[t] = scsh[t]; shb[t] = scsh[64 + t]; }
    __syncthreads();

    int pl = t & 127;          // pixel within block
    int chalf = t >> 7;        // 0 or 1 -> channels 32*chalf..+32
    int hw = hw0 + pl;
    size_t gpx = (size_t)base + pl;

    unsigned pk[16];
    #pragma unroll
    for (int c = 0; c < 32; ++c) {
        int ch = chalf * 32 + c;
        size_t idx = ((size_t)(b * 64 + ch)) * HW_ + hw;
        float a = A[idx];
        float v = fmaxf(fmaf(a, scb[ch], shb[ch]), 0.f);
        unsigned bf = f2bf(v);
        if (c & 1) pk[c >> 1] |= bf << 16; else pk[c >> 1] = bf;
    }
    unsigned short* dst = Abf + (gpx << 6) + chalf * 32;
    #pragma unroll
    for (int j = 0; j < 4; ++j)
        *(int4*)&dst[j * 8] = make_int4((int)pk[4 * j], (int)pk[4 * j + 1],
                                        (int)pk[4 * j + 2], (int)pk[4 * j + 3]);
}

// ---------------------------------------------------------------------------
// offset conv3x3 via bf16 MFMA on Abf (NHWC): implicit GEMM, zero pad.
// ---------------------------------------------------------------------------
__global__ __launch_bounds__(64) void k_offconv(const unsigned short* __restrict__ Abf,
        const unsigned short* __restrict__ wOff, const float* __restrict__ ob,
        float* __restrict__ off)
{
    int t = threadIdx.x;
    int wg = blockIdx.x;
    int nid = (wg & 7) * 576 + (wg >> 3);        // XCD-chunked over 4608
    int base = nid * 16;
    int b = base / HW_;
    int hw0 = base % HW_;
    int h = hw0 / W_;
    int w0 = hw0 % W_;

    int m = t & 15, q = t >> 4;
    int wx = w0 + m;
    const unsigned short* Ap = Abf + (((size_t)b * HW_) << 6);
    int cA = q * 8, cB = 32 + q * 8;

    f4v acc0 = (f4v){0.f, 0.f, 0.f, 0.f};
    f4v acc1 = (f4v){0.f, 0.f, 0.f, 0.f};
    const s8v zr = {0, 0, 0, 0, 0, 0, 0, 0};

    #pragma unroll
    for (int k = 0; k < 9; ++k) {
        int yy = h + k / 3 - 1;
        int xx = wx + k % 3 - 1;
        bool valid = (yy >= 0) && (yy < H_) && (xx >= 0) && (xx < W_);
        int yc = min(max(yy, 0), H_ - 1);
        int xc = min(max(xx, 0), W_ - 1);
        size_t ip = (size_t)(yc * W_ + xc) << 6;
        s8v a0 = *(const s8v*)&Ap[ip + cA];
        s8v a1 = *(const s8v*)&Ap[ip + cB];
        if (!valid) { a0 = zr; a1 = zr; }

        const unsigned short* wb = wOff + ((size_t)k << 11);
        s8v b00 = *(const s8v*)&wb[m * 64 + q * 8];
        s8v b01 = *(const s8v*)&wb[m * 64 + 32 + q * 8];
        s8v b10 = *(const s8v*)&wb[(16 + m) * 64 + q * 8];
        s8v b11 = *(const s8v*)&wb[(16 + m) * 64 + 32 + q * 8];

        acc0 = __builtin_amdgcn_mfma_f32_16x16x32_bf16(a0, b00, acc0, 0, 0, 0);
        acc0 = __builtin_amdgcn_mfma_f32_16x16x32_bf16(a1, b01, acc0, 0, 0, 0);
        acc1 = __builtin_amdgcn_mfma_f32_16x16x32_bf16(a0, b10, acc1, 0, 0, 0);
        acc1 = __builtin_amdgcn_mfma_f32_16x16x32_bf16(a1, b11, acc1, 0, 0, 0);
    }

    float biasLo = ob[m];
    float biasHi = (m < 2) ? ob[16 + m] : 0.f;
    #pragma unroll
    for (int r = 0; r < 4; ++r) {
        int px = q * 4 + r;
        off[((size_t)b * 18 + m) * HW_ + hw0 + px] = acc0[r] + biasLo;
        if (m < 2)
            off[((size_t)b * 18 + 16 + m) * HW_ + hw0 + px] = acc1[r] + biasHi;
    }
}

// ---------------------------------------------------------------------------
// R13a: bilinear gather -> V[k][pixL][64] bf16, per pixel chunk.
// LANE SWIZZLE (R12 post-mortem): lanes 0-3 = same pixel, 4 channel groups.
// Per corner-load instruction a wave touches 16 pixels x 2 lines = 32 L1
// transactions (vs 64), every 64B line fully consumed; V writes coalesce to
// contiguous 128B per 4-lane group.
// ---------------------------------------------------------------------------
__global__ __launch_bounds__(256) void k_gather(const unsigned short* __restrict__ Abf,
        const float* __restrict__ offb, unsigned short* __restrict__ V,
        int basePix, int P)
{
    int t = threadIdx.x;
    int wg = blockIdx.x;
    int nblk = (P >> 6) * 9;
    int nid = (wg & 7) * (nblk >> 3) + (wg >> 3);   // XCD-chunked
    int pixblk = nid / 9;
    int k = nid - pixblk * 9;

    int pl = t >> 2;                 // pixel 0..63 within block
    int cg = t & 3;                  // 16-ch group 0..3
    int pixL = pixblk * 64 + pl;
    int gp = basePix + pixL;
    int b = gp / HW_;
    int hw = gp - b * HW_;
    int h = hw / W_;
    int wx = hw - h * W_;

    float dy = offb[(b * 18 + 2 * k) * HW_ + hw];
    float dx = offb[(b * 18 + 2 * k + 1) * HW_ + hw];
    float py = (float)(h + k / 3 - 1) + dy;
    float px = (float)(wx + k % 3 - 1) + dx;
    float fly = floorf(py), flx = floorf(px);
    float fy = py - fly, fx = px - flx;
    int y0i = (int)fly, x0i = (int)flx;
    float w00 = (1.f - fy) * (1.f - fx);
    float w01 = (1.f - fy) * fx;
    float w10 = fy * (1.f - fx);
    float w11 = fy * fx;
    bool yv0 = (y0i >= 0) && (y0i < H_);
    bool yv1 = (y0i + 1 >= 0) && (y0i + 1 < H_);
    bool xv0 = (x0i >= 0) && (x0i < W_);
    bool xv1 = (x0i + 1 >= 0) && (x0i + 1 < W_);
    if (!(yv0 && xv0)) w00 = 0.f;
    if (!(yv0 && xv1)) w01 = 0.f;
    if (!(yv1 && xv0)) w10 = 0.f;
    if (!(yv1 && xv1)) w11 = 0.f;
    int yc0 = min(max(y0i, 0), H_ - 1), yc1 = min(max(y0i + 1, 0), H_ - 1);
    int xc0 = min(max(x0i, 0), W_ - 1), xc1 = min(max(x0i + 1, 0), W_ - 1);
    size_t i00 = (size_t)(yc0 * W_ + xc0) << 6;
    size_t i01 = (size_t)(yc0 * W_ + xc1) << 6;
    size_t i10 = (size_t)(yc1 * W_ + xc0) << 6;
    size_t i11 = (size_t)(yc1 * W_ + xc1) << 6;

    const unsigned short* Ap = Abf + (((size_t)b * HW_) << 6);
    int c0 = cg * 16;
    s8v v00a = *(const s8v*)&Ap[i00 + c0], v00b = *(const s8v*)&Ap[i00 + c0 + 8];
    s8v v01a = *(const s8v*)&Ap[i01 + c0], v01b = *(const s8v*)&Ap[i01 + c0 + 8];
    s8v v10a = *(const s8v*)&Ap[i10 + c0], v10b = *(const s8v*)&Ap[i10 + c0 + 8];
    s8v v11a = *(const s8v*)&Ap[i11 + c0], v11b = *(const s8v*)&Ap[i11 + c0 + 8];

    unsigned pk[8];
    #pragma unroll
    for (int i = 0; i < 4; ++i) {
        unsigned wa = 0, wb = 0;
        #pragma unroll
        for (int jj = 0; jj < 2; ++jj) {
            int e = 2 * i + jj;
            float va = bf2f((unsigned short)v00a[e]) * w00
                     + bf2f((unsigned short)v01a[e]) * w01
                     + bf2f((unsigned short)v10a[e]) * w10
                     + bf2f((unsigned short)v11a[e]) * w11;
            wa |= ((unsigned)f2bf(va)) << (16 * jj);
            float vb = bf2f((unsigned short)v00b[e]) * w00
                     + bf2f((unsigned short)v01b[e]) * w01
                     + bf2f((unsigned short)v10b[e]) * w10
                     + bf2f((unsigned short)v11b[e]) * w11;
            wb |= ((unsigned)f2bf(vb)) << (16 * jj);
        }
        pk[i] = wa; pk[4 + i] = wb;
    }
    unsigned short* dst = V + ((((size_t)k * P + pixL) << 6) + c0);
    *(int4*)dst       = make_int4((int)pk[0], (int)pk[1], (int)pk[2], (int)pk[3]);
    *(int4*)(dst + 8) = make_int4((int)pk[4], (int)pk[5], (int)pk[6], (int)pk[7]);
}

// ---------------------------------------------------------------------------
// R13b: streaming MFMA GEMM over V (L2-resident at CH=4):
// out[px][oc] = sum_k sum_c V[k][px][c] * W[k][oc][c].
// 1 wave/block = 16px x 64oc; A loads LINEAR coalesced dwordx4.
// ---------------------------------------------------------------------------
__global__ __launch_bounds__(64) void k_dgemm(const unsigned short* __restrict__ V,
        const unsigned short* __restrict__ wkT, const float* __restrict__ beff,
        float* __restrict__ out, int basePix, int P)
{
    int t = threadIdx.x;
    int wg = blockIdx.x;
    int nblk = P >> 4;
    int nid = (wg & 7) * (nblk >> 3) + (wg >> 3);   // XCD-chunked
    int pixW = nid * 16;

    int m = t & 15, q = t >> 4;

    f4v acc[4];
    #pragma unroll
    for (int n = 0; n < 4; ++n) acc[n] = (f4v){0.f, 0.f, 0.f, 0.f};

    #pragma unroll
    for (int k = 0; k < 9; ++k) {
        const unsigned short* Vk = V + (((size_t)k * P + pixW) << 6);
        s8v a0 = *(const s8v*)&Vk[(m << 6) + q * 8];
        s8v a1 = *(const s8v*)&Vk[(m << 6) + 32 + q * 8];
        const unsigned short* wkb = wkT + ((size_t)k << 12);
        #pragma unroll
        for (int n = 0; n < 4; ++n) {
            int oc = n * 16 + m;
            s8v b0 = *(const s8v*)&wkb[oc * 64 + q * 8];
            s8v b1 = *(const s8v*)&wkb[oc * 64 + 32 + q * 8];
            acc[n] = __builtin_amdgcn_mfma_f32_16x16x32_bf16(a0, b0, acc[n], 0, 0, 0);
            acc[n] = __builtin_amdgcn_mfma_f32_16x16x32_bf16(a1, b1, acc[n], 0, 0, 0);
        }
    }

    int gp0 = basePix + pixW;
    int b = gp0 / HW_;
    int hw0 = gp0 - b * HW_;
    #pragma unroll
    for (int n = 0; n < 4; ++n) {
        int oc = n * 16 + m;
        float bias = beff[oc];
        #pragma unroll
        for (int r = 0; r < 4; ++r)
            out[((size_t)b * 64 + oc) * HW_ + hw0 + q * 4 + r] = acc[n][r] + bias;
    }
}

// ---------------------------------------------------------------------------
extern "C" void kernel_launch(void* const* d_in, const int* in_sizes, int n_in,
                              void* d_out, int out_size, void* d_ws, size_t ws_size,
                              hipStream_t stream)
{
    const float* x   = (const float*)d_in[0];
    const float* w1  = (const float*)d_in[1];
    const float* b1  = (const float*)d_in[2];
    const float* g1  = (const float*)d_in[3];
    const float* be1 = (const float*)d_in[4];
    const float* ow  = (const float*)d_in[5];
    const float* ob  = (const float*)d_in[6];
    const float* dw  = (const float*)d_in[7];
    const float* db  = (const float*)d_in[8];
    const float* w2  = (const float*)d_in[9];
    const float* b2  = (const float*)d_in[10];
    const float* g2  = (const float*)d_in[11];
    const float* be2 = (const float*)d_in[12];
    float* out = (float*)d_out;

    float* ws    = (float*)d_ws;
    float* A     = ws;                           // conv1x1 out (raw fp32)
    float* offb  = A + (size_t)NPIX_ * 64;       // 1,327,104 floats
    float* w1t   = offb + (size_t)B_ * 18 * HW_;
    unsigned short* wkT  = (unsigned short*)(w1t + 4096);   // 36,864 bf16
    unsigned short* wOff = wkT + 9 * 4096;                   // 18,432 bf16
    float* beff  = (float*)(wOff + 9 * 2048);
    float* scsh1 = beff + 64;                    // 128
    float* scsh2 = scsh1 + 128;                  // 128
    unsigned short* Abf = (unsigned short*)(scsh2 + 128);   // NPIX_*64 bf16
    unsigned short* V   = Abf + (size_t)NPIX_ * 64;          // gather staging

    // chunking: CH=4 keeps V (21.2MB) L2-resident (2.65MB/XCD); fall back to
    // CH=8 only if the workspace is unexpectedly small. Deterministic.
    size_t baseBytes = (size_t)((char*)(V) - (char*)d_ws);
    int CH = 4;
    if (ws_size < baseBytes + (size_t)9 * (NPIX_ / 4) * 64 * 2) CH = 8;
    int P = NPIX_ / CH;

    hipLaunchKernelGGL(k_fold, dim3(144), dim3(256), 0, stream,
                       w1, w2, dw, db, b2, ow, w1t, wkT, wOff, beff);
    hipLaunchKernelGGL(k_conv1x1, dim3(NPIX_ / 64), dim3(256), 0, stream,
                       x, w1t, b1, A);
    hipLaunchKernelGGL(k_stats, dim3(64), dim3(256), 0, stream, A, g1, be1, scsh1);
    hipLaunchKernelGGL(k_bntr, dim3(NPIX_ / 128), dim3(256), 0, stream,
                       A, scsh1, Abf);
    hipLaunchKernelGGL(k_offconv, dim3(NPIX_ / 16), dim3(64), 0, stream,
                       Abf, wOff, ob, offb);
    for (int cp = 0; cp < CH; ++cp) {
        hipLaunchKernelGGL(k_gather, dim3((P / 64) * 9), dim3(256), 0, stream,
                           Abf, offb, V, cp * P, P);
        hipLaunchKernelGGL(k_dgemm, dim3(P / 16), dim3(64), 0, stream,
                           V, wkT, beff, out, cp * P, P);
    }
    hipLaunchKernelGGL(k_stats, dim3(64), dim3(256), 0, stream, out, g2, be2, scsh2);
    hipLaunchKernelGGL(k_bn, dim3((NPIX_ * 64 / 4) / 256), dim3(256), 0, stream,
                       out, scsh2, 0);
}

// Round 14
// 158.417 us; speedup vs baseline: 1.4532x; 1.3401x over previous
//
#include <hip/hip_runtime.h>
#include <math.h>

#define H_ 192
#define W_ 192
#define HW_ (H_*W_)      // 36864
#define B_ 2
#define C_ 64
#define NPIX_ (B_*HW_)   // 73728
#define EPSV 1e-5f

typedef short s8v  __attribute__((ext_vector_type(8)));
typedef float f4v  __attribute__((ext_vector_type(4)));

__device__ __forceinline__ unsigned short f2bf(float f) {
    union { float f; unsigned u; } x; x.f = f;
    unsigned r = x.u + 0x7fffu + ((x.u >> 16) & 1u);   // RNE
    return (unsigned short)(r >> 16);
}
__device__ __forceinline__ float bf2f(unsigned short h) {
    union { unsigned u; float f; } x; x.u = ((unsigned)h) << 16; return x.f;
}

// ---------------------------------------------------------------------------
// Fold: w1t[c][o] = w1[o][c];
//       wkT[k][p][c]  = bf16( sum_o w2[p,o]*dw[o,c,k] )   (deform weights)
//       wOff[k][oc32][c] = bf16( ow[oc][c][k] ), oc>=18 zero  (offconv weights)
//       beff[p] = sum_o w2[p,o]*db[o] + b2[p]
// ---------------------------------------------------------------------------
__global__ void k_fold(const float* __restrict__ w1, const float* __restrict__ w2,
                       const float* __restrict__ dw, const float* __restrict__ db,
                       const float* __restrict__ b2, const float* __restrict__ ow,
                       float* __restrict__ w1t, unsigned short* __restrict__ wkT,
                       unsigned short* __restrict__ wOff, float* __restrict__ beff)
{
    int tid = blockIdx.x * 256 + threadIdx.x;   // 0..36863
    if (tid < 9 * 64 * 64) {
        int k = tid >> 12;
        int r = tid & 4095;
        int c = r >> 6;
        int p = r & 63;
        float acc = 0.f;
        #pragma unroll 8
        for (int o = 0; o < 64; ++o)
            acc = fmaf(w2[p * 64 + o], dw[(o * 64 + c) * 9 + k], acc);
        wkT[(k << 12) + (p << 6) + c] = f2bf(acc);
    }
    if (tid < 9 * 32 * 64) {       // offconv weights, padded to 32 oc
        int k = tid >> 11;
        int r = tid & 2047;
        int oc = r >> 6;
        int c = r & 63;
        float v = (oc < 18) ? ow[((oc * 64) + c) * 9 + k] : 0.f;
        wOff[tid] = f2bf(v);
    }
    if (tid < 4096) {
        int c = tid >> 6, o = tid & 63;
        w1t[c * 64 + o] = w1[o * 64 + c];
    }
    if (tid < 64) {
        float acc = b2[tid];
        #pragma unroll 8
        for (int o = 0; o < 64; ++o) acc = fmaf(w2[tid * 64 + o], db[o], acc);
        beff[tid] = acc;
    }
}

// ---------------------------------------------------------------------------
// conv1x1 #1 (fp32 VALU): y = x * w1t + b1  (raw, pre-BN)
// ---------------------------------------------------------------------------
__global__ __launch_bounds__(256) void k_conv1x1(const float* __restrict__ x,
        const float* __restrict__ w1t, const float* __restrict__ b1,
        float* __restrict__ y)
{
    __shared__ __align__(16) float xs[64][64];   // [c][p]
    __shared__ __align__(16) float wsh[64][64];  // [c][o]
    int t = threadIdx.x;
    int base = blockIdx.x * 64;
    int b = base / HW_;
    int hw0 = base % HW_;

    #pragma unroll
    for (int i = 0; i < 16; ++i) {
        int e = t + i * 256;
        ((float*)wsh)[e] = w1t[e];
    }
    int p = t & 63, cg = t >> 6;
    #pragma unroll
    for (int i = 0; i < 16; ++i) {
        int c = cg * 16 + i;
        xs[c][p] = x[(b * 64 + c) * HW_ + hw0 + p];
    }
    __syncthreads();

    int l = t & 63, wv = t >> 6;
    int pg = l & 15;
    int og = wv * 4 + (l >> 4);
    float acc[4][4];
    #pragma unroll
    for (int i = 0; i < 4; ++i)
        #pragma unroll
        for (int j = 0; j < 4; ++j) acc[i][j] = 0.f;

    #pragma unroll 8
    for (int c = 0; c < 64; ++c) {
        float va[4], wa[4];
        *(float4*)va = *(const float4*)&xs[c][pg * 4];
        *(float4*)wa = *(const float4*)&wsh[c][og * 4];
        #pragma unroll
        for (int i = 0; i < 4; ++i)
            #pragma unroll
            for (int j = 0; j < 4; ++j)
                acc[i][j] = fmaf(va[i], wa[j], acc[i][j]);
    }

    #pragma unroll
    for (int j = 0; j < 4; ++j) {
        int oc = og * 4 + j;
        float bias = b1[oc];
        float4 o4 = make_float4(acc[0][j] + bias, acc[1][j] + bias,
                                acc[2][j] + bias, acc[3][j] + bias);
        *(float4*)&y[(b * 64 + oc) * HW_ + hw0 + pg * 4] = o4;
    }
}

// ---------------------------------------------------------------------------
// BN stats two-stage. Stage P: 512 blocks = 64 ch x 8 hw-slices -> partials.
// ---------------------------------------------------------------------------
__global__ __launch_bounds__(256) void k_statsP(const float* __restrict__ y,
                                                float* __restrict__ part)
{
    int c = blockIdx.x >> 3, sl = blockIdx.x & 7;
    int t = threadIdx.x;
    float s = 0.f, sq = 0.f;
    for (int b = 0; b < B_; ++b) {
        const float4* p4 = (const float4*)&y[(b * 64 + c) * HW_ + sl * (HW_ / 8)];
        for (int i = t; i < HW_ / 8 / 4; i += 256) {
            float4 v = p4[i];
            s += v.x + v.y + v.z + v.w;
            sq += v.x * v.x + v.y * v.y + v.z * v.z + v.w * v.w;
        }
    }
    int lane = t & 63, wv = t >> 6;
    #pragma unroll
    for (int off = 32; off > 0; off >>= 1) {
        s += __shfl_down(s, off);
        sq += __shfl_down(sq, off);
    }
    __shared__ float red[8];
    if (lane == 0) { red[wv] = s; red[4 + wv] = sq; }
    __syncthreads();
    if (t == 0) {
        part[c * 8 + sl]       = red[0] + red[1] + red[2] + red[3];
        part[512 + c * 8 + sl] = red[4] + red[5] + red[6] + red[7];
    }
}

// Stage F: one tiny block -> scale/shift
__global__ void k_statsF(const float* __restrict__ part, const float* __restrict__ g,
                         const float* __restrict__ be, float* __restrict__ scsh)
{
    int c = threadIdx.x;
    if (c < 64) {
        float S = 0.f, Q = 0.f;
        #pragma unroll
        for (int sl = 0; sl < 8; ++sl) {
            S += part[c * 8 + sl];
            Q += part[512 + c * 8 + sl];
        }
        float m = S / (float)NPIX_;
        float var = Q / (float)NPIX_ - m * m;
        float sc = g[c] * rsqrtf(var + EPSV);
        scsh[c] = sc;
        scsh[64 + c] = be[c] - m * sc;
    }
}

// ---------------------------------------------------------------------------
// BN apply, in place, float4 (final BN2 apply)
// ---------------------------------------------------------------------------
__global__ void k_bn(float* __restrict__ y, const float* __restrict__ scsh, int relu)
{
    int idx = blockIdx.x * 256 + threadIdx.x;         // float4 index
    int c = ((idx * 4) / HW_) & 63;
    float sc = scsh[c], sh = scsh[64 + c];
    float4 v = ((float4*)y)[idx];
    v.x = fmaf(v.x, sc, sh);
    v.y = fmaf(v.y, sc, sh);
    v.z = fmaf(v.z, sc, sh);
    v.w = fmaf(v.w, sc, sh);
    if (relu) {
        v.x = fmaxf(v.x, 0.f); v.y = fmaxf(v.y, 0.f);
        v.z = fmaxf(v.z, 0.f); v.w = fmaxf(v.w, 0.f);
    }
    ((float4*)y)[idx] = v;
}

// ---------------------------------------------------------------------------
// BN1+ReLU -> bf16 NHWC copy ONLY. Thread = 32 ch of one pixel.
// ---------------------------------------------------------------------------
__global__ __launch_bounds__(256) void k_bntr(const float* __restrict__ A,
        const float* __restrict__ scsh, unsigned short* __restrict__ Abf)
{
    __shared__ float scb[64], shb[64];
    int t = threadIdx.x;
    int wg = blockIdx.x;
    int nid = (wg & 7) * 72 + (wg >> 3);     // XCD-chunked over 576
    int base = nid * 128;                    // global pixel base
    int b = base / HW_;
    int hw0 = base % HW_;

    if (t < 64) { scb[t] = scsh[t]; shb[t] = scsh[64 + t]; }
    __syncthreads();

    int pl = t & 127;          // pixel within block
    int chalf = t >> 7;        // 0 or 1 -> channels 32*chalf..+32
    int hw = hw0 + pl;
    size_t gpx = (size_t)base + pl;

    unsigned pk[16];
    #pragma unroll
    for (int c = 0; c < 32; ++c) {
        int ch = chalf * 32 + c;
        size_t idx = ((size_t)(b * 64 + ch)) * HW_ + hw;
        float a = A[idx];
        float v = fmaxf(fmaf(a, scb[ch], shb[ch]), 0.f);
        unsigned bf = f2bf(v);
        if (c & 1) pk[c >> 1] |= bf << 16; else pk[c >> 1] = bf;
    }
    unsigned short* dst = Abf + (gpx << 6) + chalf * 32;
    #pragma unroll
    for (int j = 0; j < 4; ++j)
        *(int4*)&dst[j * 8] = make_int4((int)pk[4 * j], (int)pk[4 * j + 1],
                                        (int)pk[4 * j + 2], (int)pk[4 * j + 3]);
}

// ---------------------------------------------------------------------------
// offset conv3x3 via bf16 MFMA on Abf (NHWC): implicit GEMM, zero pad.
// ---------------------------------------------------------------------------
__global__ __launch_bounds__(64) void k_offconv(const unsigned short* __restrict__ Abf,
        const unsigned short* __restrict__ wOff, const float* __restrict__ ob,
        float* __restrict__ off)
{
    int t = threadIdx.x;
    int wg = blockIdx.x;
    int nid = (wg & 7) * 576 + (wg >> 3);        // XCD-chunked over 4608
    int base = nid * 16;
    int b = base / HW_;
    int hw0 = base % HW_;
    int h = hw0 / W_;
    int w0 = hw0 % W_;

    int m = t & 15, q = t >> 4;
    int wx = w0 + m;
    const unsigned short* Ap = Abf + (((size_t)b * HW_) << 6);
    int cA = q * 8, cB = 32 + q * 8;

    f4v acc0 = (f4v){0.f, 0.f, 0.f, 0.f};
    f4v acc1 = (f4v){0.f, 0.f, 0.f, 0.f};
    const s8v zr = {0, 0, 0, 0, 0, 0, 0, 0};

    #pragma unroll
    for (int k = 0; k < 9; ++k) {
        int yy = h + k / 3 - 1;
        int xx = wx + k % 3 - 1;
        bool valid = (yy >= 0) && (yy < H_) && (xx >= 0) && (xx < W_);
        int yc = min(max(yy, 0), H_ - 1);
        int xc = min(max(xx, 0), W_ - 1);
        size_t ip = (size_t)(yc * W_ + xc) << 6;
        s8v a0 = *(const s8v*)&Ap[ip + cA];
        s8v a1 = *(const s8v*)&Ap[ip + cB];
        if (!valid) { a0 = zr; a1 = zr; }

        const unsigned short* wb = wOff + ((size_t)k << 11);
        s8v b00 = *(const s8v*)&wb[m * 64 + q * 8];
        s8v b01 = *(const s8v*)&wb[m * 64 + 32 + q * 8];
        s8v b10 = *(const s8v*)&wb[(16 + m) * 64 + q * 8];
        s8v b11 = *(const s8v*)&wb[(16 + m) * 64 + 32 + q * 8];

        acc0 = __builtin_amdgcn_mfma_f32_16x16x32_bf16(a0, b00, acc0, 0, 0, 0);
        acc0 = __builtin_amdgcn_mfma_f32_16x16x32_bf16(a1, b01, acc0, 0, 0, 0);
        acc1 = __builtin_amdgcn_mfma_f32_16x16x32_bf16(a0, b10, acc1, 0, 0, 0);
        acc1 = __builtin_amdgcn_mfma_f32_16x16x32_bf16(a1, b11, acc1, 0, 0, 0);
    }

    float biasLo = ob[m];
    float biasHi = (m < 2) ? ob[16 + m] : 0.f;
    #pragma unroll
    for (int r = 0; r < 4; ++r) {
        int px = q * 4 + r;
        off[((size_t)b * 18 + m) * HW_ + hw0 + px] = acc0[r] + biasLo;
        if (m < 2)
            off[((size_t)b * 18 + 16 + m) * HW_ + hw0 + px] = acc1[r] + biasHi;
    }
}

// ---------------------------------------------------------------------------
// R14a: bilinear gather -> V[k][pix][64] bf16, WHOLE image in one launch.
// Lanes 0-3 = same pixel, 4 channel groups (coalesced; R13 swizzle).
// 10368 blocks -> pure TLP hides gather latency.
// ---------------------------------------------------------------------------
__global__ __launch_bounds__(256) void k_gather(const unsigned short* __restrict__ Abf,
        const float* __restrict__ offb, unsigned short* __restrict__ V)
{
    const int P = NPIX_;
    int t = threadIdx.x;
    int wg = blockIdx.x;
    const int nblk = (P >> 6) * 9;                  // 10368
    int nid = (wg & 7) * (nblk >> 3) + (wg >> 3);   // XCD-chunked
    int pixblk = nid / 9;
    int k = nid - pixblk * 9;

    int pl = t >> 2;                 // pixel 0..63 within block
    int cg = t & 3;                  // 16-ch group 0..3
    int gp = pixblk * 64 + pl;
    int b = gp / HW_;
    int hw = gp - b * HW_;
    int h = hw / W_;
    int wx = hw - h * W_;

    float dy = offb[(b * 18 + 2 * k) * HW_ + hw];
    float dx = offb[(b * 18 + 2 * k + 1) * HW_ + hw];
    float py = (float)(h + k / 3 - 1) + dy;
    float px = (float)(wx + k % 3 - 1) + dx;
    float fly = floorf(py), flx = floorf(px);
    float fy = py - fly, fx = px - flx;
    int y0i = (int)fly, x0i = (int)flx;
    float w00 = (1.f - fy) * (1.f - fx);
    float w01 = (1.f - fy) * fx;
    float w10 = fy * (1.f - fx);
    float w11 = fy * fx;
    bool yv0 = (y0i >= 0) && (y0i < H_);
    bool yv1 = (y0i + 1 >= 0) && (y0i + 1 < H_);
    bool xv0 = (x0i >= 0) && (x0i < W_);
    bool xv1 = (x0i + 1 >= 0) && (x0i + 1 < W_);
    if (!(yv0 && xv0)) w00 = 0.f;
    if (!(yv0 && xv1)) w01 = 0.f;
    if (!(yv1 && xv0)) w10 = 0.f;
    if (!(yv1 && xv1)) w11 = 0.f;
    int yc0 = min(max(y0i, 0), H_ - 1), yc1 = min(max(y0i + 1, 0), H_ - 1);
    int xc0 = min(max(x0i, 0), W_ - 1), xc1 = min(max(x0i + 1, 0), W_ - 1);
    size_t i00 = (size_t)(yc0 * W_ + xc0) << 6;
    size_t i01 = (size_t)(yc0 * W_ + xc1) << 6;
    size_t i10 = (size_t)(yc1 * W_ + xc0) << 6;
    size_t i11 = (size_t)(yc1 * W_ + xc1) << 6;

    const unsigned short* Ap = Abf + (((size_t)b * HW_) << 6);
    int c0 = cg * 16;
    s8v v00a = *(const s8v*)&Ap[i00 + c0], v00b = *(const s8v*)&Ap[i00 + c0 + 8];
    s8v v01a = *(const s8v*)&Ap[i01 + c0], v01b = *(const s8v*)&Ap[i01 + c0 + 8];
    s8v v10a = *(const s8v*)&Ap[i10 + c0], v10b = *(const s8v*)&Ap[i10 + c0 + 8];
    s8v v11a = *(const s8v*)&Ap[i11 + c0], v11b = *(const s8v*)&Ap[i11 + c0 + 8];

    unsigned pk[8];
    #pragma unroll
    for (int i = 0; i < 4; ++i) {
        unsigned wa = 0, wb = 0;
        #pragma unroll
        for (int jj = 0; jj < 2; ++jj) {
            int e = 2 * i + jj;
            float va = bf2f((unsigned short)v00a[e]) * w00
                     + bf2f((unsigned short)v01a[e]) * w01
                     + bf2f((unsigned short)v10a[e]) * w10
                     + bf2f((unsigned short)v11a[e]) * w11;
            wa |= ((unsigned)f2bf(va)) << (16 * jj);
            float vb = bf2f((unsigned short)v00b[e]) * w00
                     + bf2f((unsigned short)v01b[e]) * w01
                     + bf2f((unsigned short)v10b[e]) * w10
                     + bf2f((unsigned short)v11b[e]) * w11;
            wb |= ((unsigned)f2bf(vb)) << (16 * jj);
        }
        pk[i] = wa; pk[4 + i] = wb;
    }
    unsigned short* dst = V + ((((size_t)k * P + gp) << 6) + c0);
    *(int4*)dst       = make_int4((int)pk[0], (int)pk[1], (int)pk[2], (int)pk[3]);
    *(int4*)(dst + 8) = make_int4((int)pk[4], (int)pk[5], (int)pk[6], (int)pk[7]);
}

// ---------------------------------------------------------------------------
// R14b: streaming MFMA GEMM over V (single launch, V flows via L3):
// out[px][oc] = sum_k sum_c V[k][px][c] * W[k][oc][c].
// ---------------------------------------------------------------------------
__global__ __launch_bounds__(64) void k_dgemm(const unsigned short* __restrict__ V,
        const unsigned short* __restrict__ wkT, const float* __restrict__ beff,
        float* __restrict__ out)
{
    const int P = NPIX_;
    int t = threadIdx.x;
    int wg = blockIdx.x;
    const int nblk = P >> 4;                        // 4608
    int nid = (wg & 7) * (nblk >> 3) + (wg >> 3);   // XCD-chunked
    int pixW = nid * 16;

    int m = t & 15, q = t >> 4;

    f4v acc[4];
    #pragma unroll
    for (int n = 0; n < 4; ++n) acc[n] = (f4v){0.f, 0.f, 0.f, 0.f};

    #pragma unroll
    for (int k = 0; k < 9; ++k) {
        const unsigned short* Vk = V + (((size_t)k * P + pixW) << 6);
        s8v a0 = *(const s8v*)&Vk[(m << 6) + q * 8];
        s8v a1 = *(const s8v*)&Vk[(m << 6) + 32 + q * 8];
        const unsigned short* wkb = wkT + ((size_t)k << 12);
        #pragma unroll
        for (int n = 0; n < 4; ++n) {
            int oc = n * 16 + m;
            s8v b0 = *(const s8v*)&wkb[oc * 64 + q * 8];
            s8v b1 = *(const s8v*)&wkb[oc * 64 + 32 + q * 8];
            acc[n] = __builtin_amdgcn_mfma_f32_16x16x32_bf16(a0, b0, acc[n], 0, 0, 0);
            acc[n] = __builtin_amdgcn_mfma_f32_16x16x32_bf16(a1, b1, acc[n], 0, 0, 0);
        }
    }

    int b = pixW / HW_;
    int hw0 = pixW - b * HW_;
    #pragma unroll
    for (int n = 0; n < 4; ++n) {
        int oc = n * 16 + m;
        float bias = beff[oc];
        #pragma unroll
        for (int r = 0; r < 4; ++r)
            out[((size_t)b * 64 + oc) * HW_ + hw0 + q * 4 + r] = acc[n][r] + bias;
    }
}

// ---------------------------------------------------------------------------
extern "C" void kernel_launch(void* const* d_in, const int* in_sizes, int n_in,
                              void* d_out, int out_size, void* d_ws, size_t ws_size,
                              hipStream_t stream)
{
    const float* x   = (const float*)d_in[0];
    const float* w1  = (const float*)d_in[1];
    const float* b1  = (const float*)d_in[2];
    const float* g1  = (const float*)d_in[3];
    const float* be1 = (const float*)d_in[4];
    const float* ow  = (const float*)d_in[5];
    const float* ob  = (const float*)d_in[6];
    const float* dw  = (const float*)d_in[7];
    const float* db  = (const float*)d_in[8];
    const float* w2  = (const float*)d_in[9];
    const float* b2  = (const float*)d_in[10];
    const float* g2  = (const float*)d_in[11];
    const float* be2 = (const float*)d_in[12];
    float* out = (float*)d_out;

    float* ws    = (float*)d_ws;
    float* A     = ws;                           // conv1x1 out (raw fp32)
    float* offb  = A + (size_t)NPIX_ * 64;       // 1,327,104 floats
    float* w1t   = offb + (size_t)B_ * 18 * HW_;
    unsigned short* wkT  = (unsigned short*)(w1t + 4096);   // 36,864 bf16
    unsigned short* wOff = wkT + 9 * 4096;                   // 18,432 bf16
    float* beff  = (float*)(wOff + 9 * 2048);
    float* scsh1 = beff + 64;                    // 128
    float* scsh2 = scsh1 + 128;                  // 128
    float* part  = scsh2 + 128;                  // 1024 (stats partials)
    unsigned short* Abf = (unsigned short*)(part + 1024);   // NPIX_*64 bf16
    unsigned short* V   = Abf + (size_t)NPIX_ * 64;          // 9*NPIX_*64 bf16

    hipLaunchKernelGGL(k_fold, dim3(144), dim3(256), 0, stream,
                       w1, w2, dw, db, b2, ow, w1t, wkT, wOff, beff);
    hipLaunchKernelGGL(k_conv1x1, dim3(NPIX_ / 64), dim3(256), 0, stream,
                       x, w1t, b1, A);
    hipLaunchKernelGGL(k_statsP, dim3(512), dim3(256), 0, stream, A, part);
    hipLaunchKernelGGL(k_statsF, dim3(1), dim3(64), 0, stream,
                       part, g1, be1, scsh1);
    hipLaunchKernelGGL(k_bntr, dim3(NPIX_ / 128), dim3(256), 0, stream,
                       A, scsh1, Abf);
    hipLaunchKernelGGL(k_offconv, dim3(NPIX_ / 16), dim3(64), 0, stream,
                       Abf, wOff, ob, offb);
    hipLaunchKernelGGL(k_gather, dim3((NPIX_ / 64) * 9), dim3(256), 0, stream,
                       Abf, offb, V);
    hipLaunchKernelGGL(k_dgemm, dim3(NPIX_ / 16), dim3(64), 0, stream,
                       V, wkT, beff, out);
    hipLaunchKernelGGL(k_statsP, dim3(512), dim3(256), 0, stream, out, part);
    hipLaunchKernelGGL(k_statsF, dim3(1), dim3(64), 0, stream,
                       part, g2, be2, scsh2);
    hipLaunchKernelGGL(k_bn, dim3((NPIX_ * 64 / 4) / 256), dim3(256), 0, stream,
                       out, scsh2, 0);
}

// Round 15
// 157.163 us; speedup vs baseline: 1.4648x; 1.0080x over previous
//
#include <hip/hip_runtime.h>
#include <math.h>

#define H_ 192
#define W_ 192
#define HW_ (H_*W_)      // 36864
#define B_ 2
#define C_ 64
#define NPIX_ (B_*HW_)   // 73728
#define EPSV 1e-5f

typedef short s8v  __attribute__((ext_vector_type(8)));
typedef float f4v  __attribute__((ext_vector_type(4)));

__device__ __forceinline__ unsigned short f2bf(float f) {
    union { float f; unsigned u; } x; x.f = f;
    unsigned r = x.u + 0x7fffu + ((x.u >> 16) & 1u);   // RNE
    return (unsigned short)(r >> 16);
}
__device__ __forceinline__ float bf2f(unsigned short h) {
    union { unsigned u; float f; } x; x.u = ((unsigned)h) << 16; return x.f;
}

// ---------------------------------------------------------------------------
// Fold: w1t[c][o] = w1[o][c];
//       wkT[k][p][c]  = bf16( sum_o w2[p,o]*dw[o,c,k] )   (deform weights)
//       wOff[k][oc32][c] = bf16( ow[oc][c][k] ), oc>=18 zero  (offconv weights)
//       beff[p] = sum_o w2[p,o]*db[o] + b2[p]
// ---------------------------------------------------------------------------
__global__ void k_fold(const float* __restrict__ w1, const float* __restrict__ w2,
                       const float* __restrict__ dw, const float* __restrict__ db,
                       const float* __restrict__ b2, const float* __restrict__ ow,
                       float* __restrict__ w1t, unsigned short* __restrict__ wkT,
                       unsigned short* __restrict__ wOff, float* __restrict__ beff)
{
    int tid = blockIdx.x * 256 + threadIdx.x;   // 0..36863
    if (tid < 9 * 64 * 64) {
        int k = tid >> 12;
        int r = tid & 4095;
        int c = r >> 6;
        int p = r & 63;
        float acc = 0.f;
        #pragma unroll 8
        for (int o = 0; o < 64; ++o)
            acc = fmaf(w2[p * 64 + o], dw[(o * 64 + c) * 9 + k], acc);
        wkT[(k << 12) + (p << 6) + c] = f2bf(acc);
    }
    if (tid < 9 * 32 * 64) {       // offconv weights, padded to 32 oc
        int k = tid >> 11;
        int r = tid & 2047;
        int oc = r >> 6;
        int c = r & 63;
        float v = (oc < 18) ? ow[((oc * 64) + c) * 9 + k] : 0.f;
        wOff[tid] = f2bf(v);
    }
    if (tid < 4096) {
        int c = tid >> 6, o = tid & 63;
        w1t[c * 64 + o] = w1[o * 64 + c];
    }
    if (tid < 64) {
        float acc = b2[tid];
        #pragma unroll 8
        for (int o = 0; o < 64; ++o) acc = fmaf(w2[tid * 64 + o], db[o], acc);
        beff[tid] = acc;
    }
}

// ---------------------------------------------------------------------------
// conv1x1 #1 (fp32 VALU): y = x * w1t + b1  (raw, pre-BN)
// ---------------------------------------------------------------------------
__global__ __launch_bounds__(256) void k_conv1x1(const float* __restrict__ x,
        const float* __restrict__ w1t, const float* __restrict__ b1,
        float* __restrict__ y)
{
    __shared__ __align__(16) float xs[64][64];   // [c][p]
    __shared__ __align__(16) float wsh[64][64];  // [c][o]
    int t = threadIdx.x;
    int base = blockIdx.x * 64;
    int b = base / HW_;
    int hw0 = base % HW_;

    #pragma unroll
    for (int i = 0; i < 16; ++i) {
        int e = t + i * 256;
        ((float*)wsh)[e] = w1t[e];
    }
    int p = t & 63, cg = t >> 6;
    #pragma unroll
    for (int i = 0; i < 16; ++i) {
        int c = cg * 16 + i;
        xs[c][p] = x[(b * 64 + c) * HW_ + hw0 + p];
    }
    __syncthreads();

    int l = t & 63, wv = t >> 6;
    int pg = l & 15;
    int og = wv * 4 + (l >> 4);
    float acc[4][4];
    #pragma unroll
    for (int i = 0; i < 4; ++i)
        #pragma unroll
        for (int j = 0; j < 4; ++j) acc[i][j] = 0.f;

    #pragma unroll 8
    for (int c = 0; c < 64; ++c) {
        float va[4], wa[4];
        *(float4*)va = *(const float4*)&xs[c][pg * 4];
        *(float4*)wa = *(const float4*)&wsh[c][og * 4];
        #pragma unroll
        for (int i = 0; i < 4; ++i)
            #pragma unroll
            for (int j = 0; j < 4; ++j)
                acc[i][j] = fmaf(va[i], wa[j], acc[i][j]);
    }

    #pragma unroll
    for (int j = 0; j < 4; ++j) {
        int oc = og * 4 + j;
        float bias = b1[oc];
        float4 o4 = make_float4(acc[0][j] + bias, acc[1][j] + bias,
                                acc[2][j] + bias, acc[3][j] + bias);
        *(float4*)&y[(b * 64 + oc) * HW_ + hw0 + pg * 4] = o4;
    }
}

// ---------------------------------------------------------------------------
// BN stats two-stage. Stage P: 512 blocks = 64 ch x 8 hw-slices -> partials.
// ---------------------------------------------------------------------------
__global__ __launch_bounds__(256) void k_statsP(const float* __restrict__ y,
                                                float* __restrict__ part)
{
    int c = blockIdx.x >> 3, sl = blockIdx.x & 7;
    int t = threadIdx.x;
    float s = 0.f, sq = 0.f;
    for (int b = 0; b < B_; ++b) {
        const float4* p4 = (const float4*)&y[(b * 64 + c) * HW_ + sl * (HW_ / 8)];
        for (int i = t; i < HW_ / 8 / 4; i += 256) {
            float4 v = p4[i];
            s += v.x + v.y + v.z + v.w;
            sq += v.x * v.x + v.y * v.y + v.z * v.z + v.w * v.w;
        }
    }
    int lane = t & 63, wv = t >> 6;
    #pragma unroll
    for (int off = 32; off > 0; off >>= 1) {
        s += __shfl_down(s, off);
        sq += __shfl_down(sq, off);
    }
    __shared__ float red[8];
    if (lane == 0) { red[wv] = s; red[4 + wv] = sq; }
    __syncthreads();
    if (t == 0) {
        part[c * 8 + sl]       = red[0] + red[1] + red[2] + red[3];
        part[512 + c * 8 + sl] = red[4] + red[5] + red[6] + red[7];
    }
}

// Stage F: one tiny block -> scale/shift
__global__ void k_statsF(const float* __restrict__ part, const float* __restrict__ g,
                         const float* __restrict__ be, float* __restrict__ scsh)
{
    int c = threadIdx.x;
    if (c < 64) {
        float S = 0.f, Q = 0.f;
        #pragma unroll
        for (int sl = 0; sl < 8; ++sl) {
            S += part[c * 8 + sl];
            Q += part[512 + c * 8 + sl];
        }
        float m = S / (float)NPIX_;
        float var = Q / (float)NPIX_ - m * m;
        float sc = g[c] * rsqrtf(var + EPSV);
        scsh[c] = sc;
        scsh[64 + c] = be[c] - m * sc;
    }
}

// ---------------------------------------------------------------------------
// BN apply, in place, float4 (final BN2 apply)
// ---------------------------------------------------------------------------
__global__ void k_bn(float* __restrict__ y, const float* __restrict__ scsh, int relu)
{
    int idx = blockIdx.x * 256 + threadIdx.x;         // float4 index
    int c = ((idx * 4) / HW_) & 63;
    float sc = scsh[c], sh = scsh[64 + c];
    float4 v = ((float4*)y)[idx];
    v.x = fmaf(v.x, sc, sh);
    v.y = fmaf(v.y, sc, sh);
    v.z = fmaf(v.z, sc, sh);
    v.w = fmaf(v.w, sc, sh);
    if (relu) {
        v.x = fmaxf(v.x, 0.f); v.y = fmaxf(v.y, 0.f);
        v.z = fmaxf(v.z, 0.f); v.w = fmaxf(v.w, 0.f);
    }
    ((float4*)y)[idx] = v;
}

// ---------------------------------------------------------------------------
// BN1+ReLU -> bf16 NHWC copy ONLY. Thread = 32 ch of one pixel.
// ---------------------------------------------------------------------------
__global__ __launch_bounds__(256) void k_bntr(const float* __restrict__ A,
        const float* __restrict__ scsh, unsigned short* __restrict__ Abf)
{
    __shared__ float scb[64], shb[64];
    int t = threadIdx.x;
    int wg = blockIdx.x;
    int nid = (wg & 7) * 72 + (wg >> 3);     // XCD-chunked over 576
    int base = nid * 128;                    // global pixel base
    int b = base / HW_;
    int hw0 = base % HW_;

    if (t < 64) { scb[t] = scsh[t]; shb[t] = scsh[64 + t]; }
    __syncthreads();

    int pl = t & 127;          // pixel within block
    int chalf = t >> 7;        // 0 or 1 -> channels 32*chalf..+32
    int hw = hw0 + pl;
    size_t gpx = (size_t)base + pl;

    unsigned pk[16];
    #pragma unroll
    for (int c = 0; c < 32; ++c) {
        int ch = chalf * 32 + c;
        size_t idx = ((size_t)(b * 64 + ch)) * HW_ + hw;
        float a = A[idx];
        float v = fmaxf(fmaf(a, scb[ch], shb[ch]), 0.f);
        unsigned bf = f2bf(v);
        if (c & 1) pk[c >> 1] |= bf << 16; else pk[c >> 1] = bf;
    }
    unsigned short* dst = Abf + (gpx << 6) + chalf * 32;
    #pragma unroll
    for (int j = 0; j < 4; ++j)
        *(int4*)&dst[j * 8] = make_int4((int)pk[4 * j], (int)pk[4 * j + 1],
                                        (int)pk[4 * j + 2], (int)pk[4 * j + 3]);
}

// ---------------------------------------------------------------------------
// offset conv3x3 via bf16 MFMA on Abf (NHWC): implicit GEMM, zero pad.
// ---------------------------------------------------------------------------
__global__ __launch_bounds__(64) void k_offconv(const unsigned short* __restrict__ Abf,
        const unsigned short* __restrict__ wOff, const float* __restrict__ ob,
        float* __restrict__ off)
{
    int t = threadIdx.x;
    int wg = blockIdx.x;
    int nid = (wg & 7) * 576 + (wg >> 3);        // XCD-chunked over 4608
    int base = nid * 16;
    int b = base / HW_;
    int hw0 = base % HW_;
    int h = hw0 / W_;
    int w0 = hw0 % W_;

    int m = t & 15, q = t >> 4;
    int wx = w0 + m;
    const unsigned short* Ap = Abf + (((size_t)b * HW_) << 6);
    int cA = q * 8, cB = 32 + q * 8;

    f4v acc0 = (f4v){0.f, 0.f, 0.f, 0.f};
    f4v acc1 = (f4v){0.f, 0.f, 0.f, 0.f};
    const s8v zr = {0, 0, 0, 0, 0, 0, 0, 0};

    #pragma unroll
    for (int k = 0; k < 9; ++k) {
        int yy = h + k / 3 - 1;
        int xx = wx + k % 3 - 1;
        bool valid = (yy >= 0) && (yy < H_) && (xx >= 0) && (xx < W_);
        int yc = min(max(yy, 0), H_ - 1);
        int xc = min(max(xx, 0), W_ - 1);
        size_t ip = (size_t)(yc * W_ + xc) << 6;
        s8v a0 = *(const s8v*)&Ap[ip + cA];
        s8v a1 = *(const s8v*)&Ap[ip + cB];
        if (!valid) { a0 = zr; a1 = zr; }

        const unsigned short* wb = wOff + ((size_t)k << 11);
        s8v b00 = *(const s8v*)&wb[m * 64 + q * 8];
        s8v b01 = *(const s8v*)&wb[m * 64 + 32 + q * 8];
        s8v b10 = *(const s8v*)&wb[(16 + m) * 64 + q * 8];
        s8v b11 = *(const s8v*)&wb[(16 + m) * 64 + 32 + q * 8];

        acc0 = __builtin_amdgcn_mfma_f32_16x16x32_bf16(a0, b00, acc0, 0, 0, 0);
        acc0 = __builtin_amdgcn_mfma_f32_16x16x32_bf16(a1, b01, acc0, 0, 0, 0);
        acc1 = __builtin_amdgcn_mfma_f32_16x16x32_bf16(a0, b10, acc1, 0, 0, 0);
        acc1 = __builtin_amdgcn_mfma_f32_16x16x32_bf16(a1, b11, acc1, 0, 0, 0);
    }

    float biasLo = ob[m];
    float biasHi = (m < 2) ? ob[16 + m] : 0.f;
    #pragma unroll
    for (int r = 0; r < 4; ++r) {
        int px = q * 4 + r;
        off[((size_t)b * 18 + m) * HW_ + hw0 + px] = acc0[r] + biasLo;
        if (m < 2)
            off[((size_t)b * 18 + 16 + m) * HW_ + hw0 + px] = acc1[r] + biasHi;
    }
}

// ---------------------------------------------------------------------------
// bilinear gather -> V[k][pix][64] bf16, whole image (R14 structure).
// Lanes 0-3 = same pixel, 4 channel groups (coalesced).
// ---------------------------------------------------------------------------
__global__ __launch_bounds__(256) void k_gather(const unsigned short* __restrict__ Abf,
        const float* __restrict__ offb, unsigned short* __restrict__ V)
{
    const int P = NPIX_;
    int t = threadIdx.x;
    int wg = blockIdx.x;
    const int nblk = (P >> 6) * 9;                  // 10368
    int nid = (wg & 7) * (nblk >> 3) + (wg >> 3);   // XCD-chunked
    int pixblk = nid / 9;
    int k = nid - pixblk * 9;

    int pl = t >> 2;                 // pixel 0..63 within block
    int cg = t & 3;                  // 16-ch group 0..3
    int gp = pixblk * 64 + pl;
    int b = gp / HW_;
    int hw = gp - b * HW_;
    int h = hw / W_;
    int wx = hw - h * W_;

    float dy = offb[(b * 18 + 2 * k) * HW_ + hw];
    float dx = offb[(b * 18 + 2 * k + 1) * HW_ + hw];
    float py = (float)(h + k / 3 - 1) + dy;
    float px = (float)(wx + k % 3 - 1) + dx;
    float fly = floorf(py), flx = floorf(px);
    float fy = py - fly, fx = px - flx;
    int y0i = (int)fly, x0i = (int)flx;
    float w00 = (1.f - fy) * (1.f - fx);
    float w01 = (1.f - fy) * fx;
    float w10 = fy * (1.f - fx);
    float w11 = fy * fx;
    bool yv0 = (y0i >= 0) && (y0i < H_);
    bool yv1 = (y0i + 1 >= 0) && (y0i + 1 < H_);
    bool xv0 = (x0i >= 0) && (x0i < W_);
    bool xv1 = (x0i + 1 >= 0) && (x0i + 1 < W_);
    if (!(yv0 && xv0)) w00 = 0.f;
    if (!(yv0 && xv1)) w01 = 0.f;
    if (!(yv1 && xv0)) w10 = 0.f;
    if (!(yv1 && xv1)) w11 = 0.f;
    int yc0 = min(max(y0i, 0), H_ - 1), yc1 = min(max(y0i + 1, 0), H_ - 1);
    int xc0 = min(max(x0i, 0), W_ - 1), xc1 = min(max(x0i + 1, 0), W_ - 1);
    size_t i00 = (size_t)(yc0 * W_ + xc0) << 6;
    size_t i01 = (size_t)(yc0 * W_ + xc1) << 6;
    size_t i10 = (size_t)(yc1 * W_ + xc0) << 6;
    size_t i11 = (size_t)(yc1 * W_ + xc1) << 6;

    const unsigned short* Ap = Abf + (((size_t)b * HW_) << 6);
    int c0 = cg * 16;
    s8v v00a = *(const s8v*)&Ap[i00 + c0], v00b = *(const s8v*)&Ap[i00 + c0 + 8];
    s8v v01a = *(const s8v*)&Ap[i01 + c0], v01b = *(const s8v*)&Ap[i01 + c0 + 8];
    s8v v10a = *(const s8v*)&Ap[i10 + c0], v10b = *(const s8v*)&Ap[i10 + c0 + 8];
    s8v v11a = *(const s8v*)&Ap[i11 + c0], v11b = *(const s8v*)&Ap[i11 + c0 + 8];

    unsigned pk[8];
    #pragma unroll
    for (int i = 0; i < 4; ++i) {
        unsigned wa = 0, wb = 0;
        #pragma unroll
        for (int jj = 0; jj < 2; ++jj) {
            int e = 2 * i + jj;
            float va = bf2f((unsigned short)v00a[e]) * w00
                     + bf2f((unsigned short)v01a[e]) * w01
                     + bf2f((unsigned short)v10a[e]) * w10
                     + bf2f((unsigned short)v11a[e]) * w11;
            wa |= ((unsigned)f2bf(va)) << (16 * jj);
            float vb = bf2f((unsigned short)v00b[e]) * w00
                     + bf2f((unsigned short)v01b[e]) * w01
                     + bf2f((unsigned short)v10b[e]) * w10
                     + bf2f((unsigned short)v11b[e]) * w11;
            wb |= ((unsigned)f2bf(vb)) << (16 * jj);
        }
        pk[i] = wa; pk[4 + i] = wb;
    }
    unsigned short* dst = V + ((((size_t)k * P + gp) << 6) + c0);
    *(int4*)dst       = make_int4((int)pk[0], (int)pk[1], (int)pk[2], (int)pk[3]);
    *(int4*)(dst + 8) = make_int4((int)pk[4], (int)pk[5], (int)pk[6], (int)pk[7]);
}

// ---------------------------------------------------------------------------
// R15: LDS-staged streaming MFMA GEMM over V (T14 async-STAGE split).
// Block = 256 thr (4 waves) = 64 px. Double-buffered 8KB tap tiles in LDS.
// Per k: issue tap-k+1 global loads (regs) -> ds_read+8 MFMA on tap k ->
// ds_write tap k+1 (XOR-swizzled col ^= row&7) -> one barrier.
// ---------------------------------------------------------------------------
__global__ __launch_bounds__(256) void k_dgemm(const unsigned short* __restrict__ V,
        const unsigned short* __restrict__ wkT, const float* __restrict__ beff,
        float* __restrict__ out)
{
    __shared__ __align__(16) unsigned short Vlds[2][64 * 64];   // 2 x 8KB
    const int P = NPIX_;
    int t = threadIdx.x;
    int wg = blockIdx.x;
    const int nblk = P >> 6;                        // 1152 blocks of 64 px
    int nid = (wg & 7) * (nblk >> 3) + (wg >> 3);   // XCD-chunked
    int pix0 = nid * 64;

    int wv = t >> 6, lane = t & 63;
    int m = lane & 15, q = lane >> 4;

    // staging granule coords: thread t handles granules t and t+256
    int r0 = t >> 3, c0 = t & 7;                    // rows 0..31
    int r1 = r0 + 32;                               // rows 32..63 (same col)
    int d0 = r0 * 64 + ((c0 ^ (r0 & 7)) << 3);      // swizzled LDS dst (ushorts)
    int d1 = r1 * 64 + ((c0 ^ (r1 & 7)) << 3);

    f4v acc[4];
    #pragma unroll
    for (int n = 0; n < 4; ++n) acc[n] = (f4v){0.f, 0.f, 0.f, 0.f};

    // prologue: stage tap 0 into buf 0
    {
        const unsigned short* Vt = V + (((size_t)0 * P + pix0) << 6);
        int4 ga = *(const int4*)(Vt + t * 8);
        int4 gb = *(const int4*)(Vt + 2048 + t * 8);
        *(int4*)&Vlds[0][d0] = ga;
        *(int4*)&Vlds[0][d1] = gb;
    }
    __syncthreads();

    int rowA = wv * 16 + m;
    int sw0 = ((q       ^ (rowA & 7)) << 3);
    int sw1 = (((4 + q) ^ (rowA & 7)) << 3);

    #pragma unroll
    for (int k = 0; k < 9; ++k) {
        // ---- issue next tap's global loads FIRST (hide under MFMAs)
        int4 ga, gb;
        if (k < 8) {
            const unsigned short* Vt = V + (((size_t)(k + 1) * P + pix0) << 6);
            ga = *(const int4*)(Vt + t * 8);
            gb = *(const int4*)(Vt + 2048 + t * 8);
        }

        // ---- consume tap k from LDS
        const unsigned short* Lb = &Vlds[k & 1][rowA * 64];
        s8v a0 = *(const s8v*)&Lb[sw0];
        s8v a1 = *(const s8v*)&Lb[sw1];
        const unsigned short* wkb = wkT + ((size_t)k << 12);
        #pragma unroll
        for (int n = 0; n < 4; ++n) {
            int oc = n * 16 + m;
            s8v b0 = *(const s8v*)&wkb[oc * 64 + q * 8];
            s8v b1 = *(const s8v*)&wkb[oc * 64 + 32 + q * 8];
            acc[n] = __builtin_amdgcn_mfma_f32_16x16x32_bf16(a0, b0, acc[n], 0, 0, 0);
            acc[n] = __builtin_amdgcn_mfma_f32_16x16x32_bf16(a1, b1, acc[n], 0, 0, 0);
        }

        // ---- land next tap into the other buffer
        if (k < 8) {
            *(int4*)&Vlds[(k + 1) & 1][d0] = ga;
            *(int4*)&Vlds[(k + 1) & 1][d1] = gb;
        }
        __syncthreads();
    }

    int b = pix0 / HW_;
    int hw0 = pix0 - b * HW_ + wv * 16;
    #pragma unroll
    for (int n = 0; n < 4; ++n) {
        int oc = n * 16 + m;
        float bias = beff[oc];
        float4 o4 = make_float4(acc[n][0] + bias, acc[n][1] + bias,
                                acc[n][2] + bias, acc[n][3] + bias);
        *(float4*)&out[((size_t)b * 64 + oc) * HW_ + hw0 + q * 4] = o4;
    }
}

// ---------------------------------------------------------------------------
extern "C" void kernel_launch(void* const* d_in, const int* in_sizes, int n_in,
                              void* d_out, int out_size, void* d_ws, size_t ws_size,
                              hipStream_t stream)
{
    const float* x   = (const float*)d_in[0];
    const float* w1  = (const float*)d_in[1];
    const float* b1  = (const float*)d_in[2];
    const float* g1  = (const float*)d_in[3];
    const float* be1 = (const float*)d_in[4];
    const float* ow  = (const float*)d_in[5];
    const float* ob  = (const float*)d_in[6];
    const float* dw  = (const float*)d_in[7];
    const float* db  = (const float*)d_in[8];
    const float* w2  = (const float*)d_in[9];
    const float* b2  = (const float*)d_in[10];
    const float* g2  = (const float*)d_in[11];
    const float* be2 = (const float*)d_in[12];
    float* out = (float*)d_out;

    float* ws    = (float*)d_ws;
    float* A     = ws;                           // conv1x1 out (raw fp32)
    float* offb  = A + (size_t)NPIX_ * 64;       // 1,327,104 floats
    float* w1t   = offb + (size_t)B_ * 18 * HW_;
    unsigned short* wkT  = (unsigned short*)(w1t + 4096);   // 36,864 bf16
    unsigned short* wOff = wkT + 9 * 4096;                   // 18,432 bf16
    float* beff  = (float*)(wOff + 9 * 2048);
    float* scsh1 = beff + 64;                    // 128
    float* scsh2 = scsh1 + 128;                  // 128
    float* part  = scsh2 + 128;                  // 1024 (stats partials)
    unsigned short* Abf = (unsigned short*)(part + 1024);   // NPIX_*64 bf16
    unsigned short* V   = Abf + (size_t)NPIX_ * 64;          // 9*NPIX_*64 bf16

    hipLaunchKernelGGL(k_fold, dim3(144), dim3(256), 0, stream,
                       w1, w2, dw, db, b2, ow, w1t, wkT, wOff, beff);
    hipLaunchKernelGGL(k_conv1x1, dim3(NPIX_ / 64), dim3(256), 0, stream,
                       x, w1t, b1, A);
    hipLaunchKernelGGL(k_statsP, dim3(512), dim3(256), 0, stream, A, part);
    hipLaunchKernelGGL(k_statsF, dim3(1), dim3(64), 0, stream,
                       part, g1, be1, scsh1);
    hipLaunchKernelGGL(k_bntr, dim3(NPIX_ / 128), dim3(256), 0, stream,
                       A, scsh1, Abf);
    hipLaunchKernelGGL(k_offconv, dim3(NPIX_ / 16), dim3(64), 0, stream,
                       Abf, wOff, ob, offb);
    hipLaunchKernelGGL(k_gather, dim3((NPIX_ / 64) * 9), dim3(256), 0, stream,
                       Abf, offb, V);
    hipLaunchKernelGGL(k_dgemm, dim3(NPIX_ / 64), dim3(256), 0, stream,
                       V, wkT, beff, out);
    hipLaunchKernelGGL(k_statsP, dim3(512), dim3(256), 0, stream, out, part);
    hipLaunchKernelGGL(k_statsF, dim3(1), dim3(64), 0, stream,
                       part, g2, be2, scsh2);
    hipLaunchKernelGGL(k_bn, dim3((NPIX_ * 64 / 4) / 256), dim3(256), 0, stream,
                       out, scsh2, 0);
}

// Round 16
// 126.192 us; speedup vs baseline: 1.8243x; 1.2454x over previous
//
#include <hip/hip_runtime.h>
#include <math.h>

#define H_ 192
#define W_ 192
#define HW_ (H_*W_)      // 36864
#define B_ 2
#define C_ 64
#define NPIX_ (B_*HW_)   // 73728
#define EPSV 1e-5f

typedef short s8v  __attribute__((ext_vector_type(8)));
typedef float f4v  __attribute__((ext_vector_type(4)));

__device__ __forceinline__ unsigned short f2bf(float f) {
    union { float f; unsigned u; } x; x.f = f;
    unsigned r = x.u + 0x7fffu + ((x.u >> 16) & 1u);   // RNE
    return (unsigned short)(r >> 16);
}
__device__ __forceinline__ float bf2f(unsigned short h) {
    union { unsigned u; float f; } x; x.u = ((unsigned)h) << 16; return x.f;
}
__device__ __forceinline__ void glds16(const unsigned short* g, unsigned short* l) {
    __builtin_amdgcn_global_load_lds(
        (const __attribute__((address_space(1))) void*)g,
        (__attribute__((address_space(3))) void*)l, 16, 0, 0);
}

// ---------------------------------------------------------------------------
// Fold: w1t[c][o] = w1[o][c];
//   wkTs[k][g][oc][8] = bf16( sum_o w2[oc,o]*dw[o,c,k] ), g=c>>3 (TRANSPOSED
//   granule-major layout: glds-stageable, conflict-free ds_read)
//   wOff[k][oc32][c] = bf16( ow[oc][c][k] ), oc>=18 zero  (offconv weights)
//   beff[p] = sum_o w2[p,o]*db[o] + b2[p]
// ---------------------------------------------------------------------------
__global__ void k_fold(const float* __restrict__ w1, const float* __restrict__ w2,
                       const float* __restrict__ dw, const float* __restrict__ db,
                       const float* __restrict__ b2, const float* __restrict__ ow,
                       float* __restrict__ w1t, unsigned short* __restrict__ wkTs,
                       unsigned short* __restrict__ wOff, float* __restrict__ beff)
{
    int tid = blockIdx.x * 256 + threadIdx.x;   // 0..36863
    if (tid < 9 * 64 * 64) {
        int k = tid >> 12;
        int r = tid & 4095;
        int c = r >> 6;
        int p = r & 63;
        float acc = 0.f;
        #pragma unroll 8
        for (int o = 0; o < 64; ++o)
            acc = fmaf(w2[p * 64 + o], dw[(o * 64 + c) * 9 + k], acc);
        wkTs[(k << 12) + ((c >> 3) << 9) + (p << 3) + (c & 7)] = f2bf(acc);
    }
    if (tid < 9 * 32 * 64) {       // offconv weights, padded to 32 oc
        int k = tid >> 11;
        int r = tid & 2047;
        int oc = r >> 6;
        int c = r & 63;
        float v = (oc < 18) ? ow[((oc * 64) + c) * 9 + k] : 0.f;
        wOff[tid] = f2bf(v);
    }
    if (tid < 4096) {
        int c = tid >> 6, o = tid & 63;
        w1t[c * 64 + o] = w1[o * 64 + c];
    }
    if (tid < 64) {
        float acc = b2[tid];
        #pragma unroll 8
        for (int o = 0; o < 64; ++o) acc = fmaf(w2[tid * 64 + o], db[o], acc);
        beff[tid] = acc;
    }
}

// ---------------------------------------------------------------------------
// conv1x1 #1 (fp32 VALU): y = x * w1t + b1  (raw, pre-BN)
// ---------------------------------------------------------------------------
__global__ __launch_bounds__(256) void k_conv1x1(const float* __restrict__ x,
        const float* __restrict__ w1t, const float* __restrict__ b1,
        float* __restrict__ y)
{
    __shared__ __align__(16) float xs[64][64];   // [c][p]
    __shared__ __align__(16) float wsh[64][64];  // [c][o]
    int t = threadIdx.x;
    int base = blockIdx.x * 64;
    int b = base / HW_;
    int hw0 = base % HW_;

    #pragma unroll
    for (int i = 0; i < 16; ++i) {
        int e = t + i * 256;
        ((float*)wsh)[e] = w1t[e];
    }
    int p = t & 63, cg = t >> 6;
    #pragma unroll
    for (int i = 0; i < 16; ++i) {
        int c = cg * 16 + i;
        xs[c][p] = x[(b * 64 + c) * HW_ + hw0 + p];
    }
    __syncthreads();

    int l = t & 63, wv = t >> 6;
    int pg = l & 15;
    int og = wv * 4 + (l >> 4);
    float acc[4][4];
    #pragma unroll
    for (int i = 0; i < 4; ++i)
        #pragma unroll
        for (int j = 0; j < 4; ++j) acc[i][j] = 0.f;

    #pragma unroll 8
    for (int c = 0; c < 64; ++c) {
        float va[4], wa[4];
        *(float4*)va = *(const float4*)&xs[c][pg * 4];
        *(float4*)wa = *(const float4*)&wsh[c][og * 4];
        #pragma unroll
        for (int i = 0; i < 4; ++i)
            #pragma unroll
            for (int j = 0; j < 4; ++j)
                acc[i][j] = fmaf(va[i], wa[j], acc[i][j]);
    }

    #pragma unroll
    for (int j = 0; j < 4; ++j) {
        int oc = og * 4 + j;
        float bias = b1[oc];
        float4 o4 = make_float4(acc[0][j] + bias, acc[1][j] + bias,
                                acc[2][j] + bias, acc[3][j] + bias);
        *(float4*)&y[(b * 64 + oc) * HW_ + hw0 + pg * 4] = o4;
    }
}

// ---------------------------------------------------------------------------
// BN stats two-stage. Stage P: 512 blocks = 64 ch x 8 hw-slices -> partials.
// ---------------------------------------------------------------------------
__global__ __launch_bounds__(256) void k_statsP(const float* __restrict__ y,
                                                float* __restrict__ part)
{
    int c = blockIdx.x >> 3, sl = blockIdx.x & 7;
    int t = threadIdx.x;
    float s = 0.f, sq = 0.f;
    for (int b = 0; b < B_; ++b) {
        const float4* p4 = (const float4*)&y[(b * 64 + c) * HW_ + sl * (HW_ / 8)];
        for (int i = t; i < HW_ / 8 / 4; i += 256) {
            float4 v = p4[i];
            s += v.x + v.y + v.z + v.w;
            sq += v.x * v.x + v.y * v.y + v.z * v.z + v.w * v.w;
        }
    }
    int lane = t & 63, wv = t >> 6;
    #pragma unroll
    for (int off = 32; off > 0; off >>= 1) {
        s += __shfl_down(s, off);
        sq += __shfl_down(sq, off);
    }
    __shared__ float red[8];
    if (lane == 0) { red[wv] = s; red[4 + wv] = sq; }
    __syncthreads();
    if (t == 0) {
        part[c * 8 + sl]       = red[0] + red[1] + red[2] + red[3];
        part[512 + c * 8 + sl] = red[4] + red[5] + red[6] + red[7];
    }
}

// Stage F: one tiny block -> scale/shift
__global__ void k_statsF(const float* __restrict__ part, const float* __restrict__ g,
                         const float* __restrict__ be, float* __restrict__ scsh)
{
    int c = threadIdx.x;
    if (c < 64) {
        float S = 0.f, Q = 0.f;
        #pragma unroll
        for (int sl = 0; sl < 8; ++sl) {
            S += part[c * 8 + sl];
            Q += part[512 + c * 8 + sl];
        }
        float m = S / (float)NPIX_;
        float var = Q / (float)NPIX_ - m * m;
        float sc = g[c] * rsqrtf(var + EPSV);
        scsh[c] = sc;
        scsh[64 + c] = be[c] - m * sc;
    }
}

// ---------------------------------------------------------------------------
// BN apply, in place, float4 (final BN2 apply)
// ---------------------------------------------------------------------------
__global__ void k_bn(float* __restrict__ y, const float* __restrict__ scsh, int relu)
{
    int idx = blockIdx.x * 256 + threadIdx.x;         // float4 index
    int c = ((idx * 4) / HW_) & 63;
    float sc = scsh[c], sh = scsh[64 + c];
    float4 v = ((float4*)y)[idx];
    v.x = fmaf(v.x, sc, sh);
    v.y = fmaf(v.y, sc, sh);
    v.z = fmaf(v.z, sc, sh);
    v.w = fmaf(v.w, sc, sh);
    if (relu) {
        v.x = fmaxf(v.x, 0.f); v.y = fmaxf(v.y, 0.f);
        v.z = fmaxf(v.z, 0.f); v.w = fmaxf(v.w, 0.f);
    }
    ((float4*)y)[idx] = v;
}

// ---------------------------------------------------------------------------
// BN1+ReLU -> bf16 NHWC copy ONLY. Thread = 32 ch of one pixel.
// ---------------------------------------------------------------------------
__global__ __launch_bounds__(256) void k_bntr(const float* __restrict__ A,
        const float* __restrict__ scsh, unsigned short* __restrict__ Abf)
{
    __shared__ float scb[64], shb[64];
    int t = threadIdx.x;
    int wg = blockIdx.x;
    int nid = (wg & 7) * 72 + (wg >> 3);     // XCD-chunked over 576
    int base = nid * 128;                    // global pixel base
    int b = base / HW_;
    int hw0 = base % HW_;

    if (t < 64) { scb[t] = scsh[t]; shb[t] = scsh[64 + t]; }
    __syncthreads();

    int pl = t & 127;          // pixel within block
    int chalf = t >> 7;        // 0 or 1 -> channels 32*chalf..+32
    int hw = hw0 + pl;
    size_t gpx = (size_t)base + pl;

    unsigned pk[16];
    #pragma unroll
    for (int c = 0; c < 32; ++c) {
        int ch = chalf * 32 + c;
        size_t idx = ((size_t)(b * 64 + ch)) * HW_ + hw;
        float a = A[idx];
        float v = fmaxf(fmaf(a, scb[ch], shb[ch]), 0.f);
        unsigned bf = f2bf(v);
        if (c & 1) pk[c >> 1] |= bf << 16; else pk[c >> 1] = bf;
    }
    unsigned short* dst = Abf + (gpx << 6) + chalf * 32;
    #pragma unroll
    for (int j = 0; j < 4; ++j)
        *(int4*)&dst[j * 8] = make_int4((int)pk[4 * j], (int)pk[4 * j + 1],
                                        (int)pk[4 * j + 2], (int)pk[4 * j + 3]);
}

// ---------------------------------------------------------------------------
// offset conv3x3 via bf16 MFMA on Abf (NHWC): implicit GEMM, zero pad.
// ---------------------------------------------------------------------------
__global__ __launch_bounds__(64) void k_offconv(const unsigned short* __restrict__ Abf,
        const unsigned short* __restrict__ wOff, const float* __restrict__ ob,
        float* __restrict__ off)
{
    int t = threadIdx.x;
    int wg = blockIdx.x;
    int nid = (wg & 7) * 576 + (wg >> 3);        // XCD-chunked over 4608
    int base = nid * 16;
    int b = base / HW_;
    int hw0 = base % HW_;
    int h = hw0 / W_;
    int w0 = hw0 % W_;

    int m = t & 15, q = t >> 4;
    int wx = w0 + m;
    const unsigned short* Ap = Abf + (((size_t)b * HW_) << 6);
    int cA = q * 8, cB = 32 + q * 8;

    f4v acc0 = (f4v){0.f, 0.f, 0.f, 0.f};
    f4v acc1 = (f4v){0.f, 0.f, 0.f, 0.f};
    const s8v zr = {0, 0, 0, 0, 0, 0, 0, 0};

    #pragma unroll
    for (int k = 0; k < 9; ++k) {
        int yy = h + k / 3 - 1;
        int xx = wx + k % 3 - 1;
        bool valid = (yy >= 0) && (yy < H_) && (xx >= 0) && (xx < W_);
        int yc = min(max(yy, 0), H_ - 1);
        int xc = min(max(xx, 0), W_ - 1);
        size_t ip = (size_t)(yc * W_ + xc) << 6;
        s8v a0 = *(const s8v*)&Ap[ip + cA];
        s8v a1 = *(const s8v*)&Ap[ip + cB];
        if (!valid) { a0 = zr; a1 = zr; }

        const unsigned short* wb = wOff + ((size_t)k << 11);
        s8v b00 = *(const s8v*)&wb[m * 64 + q * 8];
        s8v b01 = *(const s8v*)&wb[m * 64 + 32 + q * 8];
        s8v b10 = *(const s8v*)&wb[(16 + m) * 64 + q * 8];
        s8v b11 = *(const s8v*)&wb[(16 + m) * 64 + 32 + q * 8];

        acc0 = __builtin_amdgcn_mfma_f32_16x16x32_bf16(a0, b00, acc0, 0, 0, 0);
        acc0 = __builtin_amdgcn_mfma_f32_16x16x32_bf16(a1, b01, acc0, 0, 0, 0);
        acc1 = __builtin_amdgcn_mfma_f32_16x16x32_bf16(a0, b10, acc1, 0, 0, 0);
        acc1 = __builtin_amdgcn_mfma_f32_16x16x32_bf16(a1, b11, acc1, 0, 0, 0);
    }

    float biasLo = ob[m];
    float biasHi = (m < 2) ? ob[16 + m] : 0.f;
    #pragma unroll
    for (int r = 0; r < 4; ++r) {
        int px = q * 4 + r;
        off[((size_t)b * 18 + m) * HW_ + hw0 + px] = acc0[r] + biasLo;
        if (m < 2)
            off[((size_t)b * 18 + 16 + m) * HW_ + hw0 + px] = acc1[r] + biasHi;
    }
}

// ---------------------------------------------------------------------------
// bilinear gather -> V[k][px][64] bf16, PRE-SWIZZLED (granule g -> g^(px&7))
// so k_dgemm can stage it with linear global_load_lds and read swizzled (T21).
// Lanes 0-3 = same pixel, 4 channel groups (coalesced at line granularity).
// ---------------------------------------------------------------------------
__global__ __launch_bounds__(256) void k_gather(const unsigned short* __restrict__ Abf,
        const float* __restrict__ offb, unsigned short* __restrict__ V)
{
    const int P = NPIX_;
    int t = threadIdx.x;
    int wg = blockIdx.x;
    const int nblk = (P >> 6) * 9;                  // 10368
    int nid = (wg & 7) * (nblk >> 3) + (wg >> 3);   // XCD-chunked
    int pixblk = nid / 9;
    int k = nid - pixblk * 9;

    int pl = t >> 2;                 // pixel 0..63 within block
    int cg = t & 3;                  // 16-ch group 0..3
    int gp = pixblk * 64 + pl;
    int b = gp / HW_;
    int hw = gp - b * HW_;
    int h = hw / W_;
    int wx = hw - h * W_;

    float dy = offb[(b * 18 + 2 * k) * HW_ + hw];
    float dx = offb[(b * 18 + 2 * k + 1) * HW_ + hw];
    float py = (float)(h + k / 3 - 1) + dy;
    float px = (float)(wx + k % 3 - 1) + dx;
    float fly = floorf(py), flx = floorf(px);
    float fy = py - fly, fx = px - flx;
    int y0i = (int)fly, x0i = (int)flx;
    float w00 = (1.f - fy) * (1.f - fx);
    float w01 = (1.f - fy) * fx;
    float w10 = fy * (1.f - fx);
    float w11 = fy * fx;
    bool yv0 = (y0i >= 0) && (y0i < H_);
    bool yv1 = (y0i + 1 >= 0) && (y0i + 1 < H_);
    bool xv0 = (x0i >= 0) && (x0i < W_);
    bool xv1 = (x0i + 1 >= 0) && (x0i + 1 < W_);
    if (!(yv0 && xv0)) w00 = 0.f;
    if (!(yv0 && xv1)) w01 = 0.f;
    if (!(yv1 && xv0)) w10 = 0.f;
    if (!(yv1 && xv1)) w11 = 0.f;
    int yc0 = min(max(y0i, 0), H_ - 1), yc1 = min(max(y0i + 1, 0), H_ - 1);
    int xc0 = min(max(x0i, 0), W_ - 1), xc1 = min(max(x0i + 1, 0), W_ - 1);
    size_t i00 = (size_t)(yc0 * W_ + xc0) << 6;
    size_t i01 = (size_t)(yc0 * W_ + xc1) << 6;
    size_t i10 = (size_t)(yc1 * W_ + xc0) << 6;
    size_t i11 = (size_t)(yc1 * W_ + xc1) << 6;

    const unsigned short* Ap = Abf + (((size_t)b * HW_) << 6);
    int c0 = cg * 16;
    s8v v00a = *(const s8v*)&Ap[i00 + c0], v00b = *(const s8v*)&Ap[i00 + c0 + 8];
    s8v v01a = *(const s8v*)&Ap[i01 + c0], v01b = *(const s8v*)&Ap[i01 + c0 + 8];
    s8v v10a = *(const s8v*)&Ap[i10 + c0], v10b = *(const s8v*)&Ap[i10 + c0 + 8];
    s8v v11a = *(const s8v*)&Ap[i11 + c0], v11b = *(const s8v*)&Ap[i11 + c0 + 8];

    unsigned pk[8];
    #pragma unroll
    for (int i = 0; i < 4; ++i) {
        unsigned wa = 0, wb = 0;
        #pragma unroll
        for (int jj = 0; jj < 2; ++jj) {
            int e = 2 * i + jj;
            float va = bf2f((unsigned short)v00a[e]) * w00
                     + bf2f((unsigned short)v01a[e]) * w01
                     + bf2f((unsigned short)v10a[e]) * w10
                     + bf2f((unsigned short)v11a[e]) * w11;
            wa |= ((unsigned)f2bf(va)) << (16 * jj);
            float vb = bf2f((unsigned short)v00b[e]) * w00
                     + bf2f((unsigned short)v01b[e]) * w01
                     + bf2f((unsigned short)v10b[e]) * w10
                     + bf2f((unsigned short)v11b[e]) * w11;
            wb |= ((unsigned)f2bf(vb)) << (16 * jj);
        }
        pk[i] = wa; pk[4 + i] = wb;
    }
    unsigned short* dst = V + (((size_t)k * P + gp) << 6);
    int sx = gp & 7;
    int g0 = (2 * cg) ^ sx;
    int g1 = (2 * cg + 1) ^ sx;
    *(int4*)&dst[g0 << 3] = make_int4((int)pk[0], (int)pk[1], (int)pk[2], (int)pk[3]);
    *(int4*)&dst[g1 << 3] = make_int4((int)pk[4], (int)pk[5], (int)pk[6], (int)pk[7]);
}

// ---------------------------------------------------------------------------
// R16: dgemm via global_load_lds + counted vmcnt + raw barriers (T3/T4/T21).
// Block = 512 thr (8 waves) = 128 px. 3 LDS buffers x (V 16KB + W 8KB).
// Per iter k: vmcnt(3) [tap k landed, tap k+1's 3 glds stay in flight] ->
// s_barrier -> issue glds tap k+2 -> ds_read V/W tap k -> 8 MFMA.
// Each wave stages the V rows it reads (own-vmcnt suffices for V); W is
// cross-wave, covered by vmcnt-before-barrier.
// ---------------------------------------------------------------------------
__global__ __launch_bounds__(512) void k_dgemm(const unsigned short* __restrict__ V,
        const unsigned short* __restrict__ wkTs, const float* __restrict__ beff,
        float* __restrict__ out)
{
    extern __shared__ unsigned short sm[];   // 3 * 12288 ushorts (72KB)
    const int P = NPIX_;
    int t = threadIdx.x;
    int wg = blockIdx.x;
    int nid = (wg & 7) * 72 + (wg >> 3);     // XCD-chunked over 576
    int pix0 = nid * 128;

    int wv = t >> 6, lane = t & 63;
    int m = lane & 15, q = lane >> 4;

    // stage tap TT into buffer BJ: 2 V-chunks + 1 W-chunk per wave (1KB glds)
#define STAGE(TT, BJ) {                                                        \
    const unsigned short* vs = V + (((size_t)(TT) * P + pix0) << 6)            \
                               + (wv * 2) * 512 + lane * 8;                    \
    unsigned short* vd = sm + (BJ) * 12288 + (wv * 2) * 512;                   \
    glds16(vs, vd);                                                            \
    glds16(vs + 512, vd + 512);                                                \
    const unsigned short* wsrc = wkTs + ((size_t)(TT) << 12) + wv * 512        \
                                 + lane * 8;                                   \
    glds16(wsrc, sm + (BJ) * 12288 + 8192 + wv * 512); }

    f4v acc[4];
    #pragma unroll
    for (int n = 0; n < 4; ++n) acc[n] = (f4v){0.f, 0.f, 0.f, 0.f};

    STAGE(0, 0);
    STAGE(1, 1);

    int rowA = wv * 16 + m;
    int sw0 = ((q       ^ (rowA & 7)) << 3);
    int sw1 = (((4 + q) ^ (rowA & 7)) << 3);

    #pragma unroll
    for (int k = 0; k < 9; ++k) {
        if (k == 8) { asm volatile("s_waitcnt vmcnt(0)" ::: "memory"); }
        else        { asm volatile("s_waitcnt vmcnt(3)" ::: "memory"); }
        __builtin_amdgcn_s_barrier();
        __builtin_amdgcn_sched_barrier(0);

        if (k < 7) {
            switch (k + 2) {   // literal tap index for constant addressing
                case 2: STAGE(2, 2); break;
                case 3: STAGE(3, 0); break;
                case 4: STAGE(4, 1); break;
                case 5: STAGE(5, 2); break;
                case 6: STAGE(6, 0); break;
                case 7: STAGE(7, 1); break;
                case 8: STAGE(8, 2); break;
            }
        }

        const unsigned short* bv = sm + (k % 3) * 12288;
        const unsigned short* bw = bv + 8192;
        s8v a0 = *(const s8v*)&bv[rowA * 64 + sw0];
        s8v a1 = *(const s8v*)&bv[rowA * 64 + sw1];
        #pragma unroll
        for (int n = 0; n < 4; ++n) {
            int oc = n * 16 + m;
            s8v b0 = *(const s8v*)&bw[(q << 9) + (oc << 3)];
            s8v b1 = *(const s8v*)&bw[((4 + q) << 9) + (oc << 3)];
            acc[n] = __builtin_amdgcn_mfma_f32_16x16x32_bf16(a0, b0, acc[n], 0, 0, 0);
            acc[n] = __builtin_amdgcn_mfma_f32_16x16x32_bf16(a1, b1, acc[n], 0, 0, 0);
        }
    }
#undef STAGE

    int b = pix0 / HW_;
    int hw0 = pix0 - b * HW_ + wv * 16;
    #pragma unroll
    for (int n = 0; n < 4; ++n) {
        int oc = n * 16 + m;
        float bias = beff[oc];
        float4 o4 = make_float4(acc[n][0] + bias, acc[n][1] + bias,
                                acc[n][2] + bias, acc[n][3] + bias);
        *(float4*)&out[((size_t)b * 64 + oc) * HW_ + hw0 + q * 4] = o4;
    }
}

// ---------------------------------------------------------------------------
extern "C" void kernel_launch(void* const* d_in, const int* in_sizes, int n_in,
                              void* d_out, int out_size, void* d_ws, size_t ws_size,
                              hipStream_t stream)
{
    const float* x   = (const float*)d_in[0];
    const float* w1  = (const float*)d_in[1];
    const float* b1  = (const float*)d_in[2];
    const float* g1  = (const float*)d_in[3];
    const float* be1 = (const float*)d_in[4];
    const float* ow  = (const float*)d_in[5];
    const float* ob  = (const float*)d_in[6];
    const float* dw  = (const float*)d_in[7];
    const float* db  = (const float*)d_in[8];
    const float* w2  = (const float*)d_in[9];
    const float* b2  = (const float*)d_in[10];
    const float* g2  = (const float*)d_in[11];
    const float* be2 = (const float*)d_in[12];
    float* out = (float*)d_out;

    float* ws    = (float*)d_ws;
    float* A     = ws;                           // conv1x1 out (raw fp32)
    float* offb  = A + (size_t)NPIX_ * 64;       // 1,327,104 floats
    float* w1t   = offb + (size_t)B_ * 18 * HW_;
    unsigned short* wkTs = (unsigned short*)(w1t + 4096);   // 36,864 bf16
    unsigned short* wOff = wkTs + 9 * 4096;                  // 18,432 bf16
    float* beff  = (float*)(wOff + 9 * 2048);
    float* scsh1 = beff + 64;                    // 128
    float* scsh2 = scsh1 + 128;                  // 128
    float* part  = scsh2 + 128;                  // 1024 (stats partials)
    unsigned short* Abf = (unsigned short*)(part + 1024);   // NPIX_*64 bf16
    unsigned short* V   = Abf + (size_t)NPIX_ * 64;          // 9*NPIX_*64 bf16

    hipLaunchKernelGGL(k_fold, dim3(144), dim3(256), 0, stream,
                       w1, w2, dw, db, b2, ow, w1t, wkTs, wOff, beff);
    hipLaunchKernelGGL(k_conv1x1, dim3(NPIX_ / 64), dim3(256), 0, stream,
                       x, w1t, b1, A);
    hipLaunchKernelGGL(k_statsP, dim3(512), dim3(256), 0, stream, A, part);
    hipLaunchKernelGGL(k_statsF, dim3(1), dim3(64), 0, stream,
                       part, g1, be1, scsh1);
    hipLaunchKernelGGL(k_bntr, dim3(NPIX_ / 128), dim3(256), 0, stream,
                       A, scsh1, Abf);
    hipLaunchKernelGGL(k_offconv, dim3(NPIX_ / 16), dim3(64), 0, stream,
                       Abf, wOff, ob, offb);
    hipLaunchKernelGGL(k_gather, dim3((NPIX_ / 64) * 9), dim3(256), 0, stream,
                       Abf, offb, V);
    hipLaunchKernelGGL(k_dgemm, dim3(NPIX_ / 128), dim3(512), 3 * 24576, stream,
                       V, wkTs, beff, out);
    hipLaunchKernelGGL(k_statsP, dim3(512), dim3(256), 0, stream, out, part);
    hipLaunchKernelGGL(k_statsF, dim3(1), dim3(64), 0, stream,
                       part, g2, be2, scsh2);
    hipLaunchKernelGGL(k_bn, dim3((NPIX_ * 64 / 4) / 256), dim3(256), 0, stream,
                       out, scsh2, 0);
}